// Round 1
// baseline (1537.132 us; speedup 1.0000x reference)
//
#include <hip/hip_runtime.h>
#include <cstdint>
#include <math.h>

#define T_TOTAL 4096
#define S_LEN   2048
#define NH      32
#define NKV     8
#define HD      128
#define HIDDEN  4096
#define QSZ     4096
#define KVSZ    1024
#define QKV_N   6144
#define SCALE_F 0.08838834764831843f   // 128^-0.5

typedef __bf16 bf16x8 __attribute__((ext_vector_type(8)));
typedef float  f32x4  __attribute__((ext_vector_type(4)));
typedef unsigned short u16;
typedef unsigned int   u32;
typedef u16 u16x8 __attribute__((ext_vector_type(8)));
typedef u16 u16x4 __attribute__((ext_vector_type(4)));

__device__ __forceinline__ u16 f2bf(float f) {
  u32 b = __float_as_uint(f);
  b += 0x7FFFu + ((b >> 16) & 1u);      // round-to-nearest-even
  return (u16)(b >> 16);
}

// async global->LDS, 16B per lane; LDS dst MUST be uniform base + lane*16
__device__ __forceinline__ void async_copy16(const u16* g, u16* l) {
  __builtin_amdgcn_global_load_lds(
      (const __attribute__((address_space(1))) void*)(g),
      (__attribute__((address_space(3))) void*)(l), 16, 0, 0);
}

// ---------------- fp32 -> bf16 cast (vectorized) ----------------
__global__ __launch_bounds__(256) void cast_bf16_kernel(const float4* __restrict__ in,
                                                        ushort4* __restrict__ out, int n4) {
  int i = blockIdx.x * 256 + threadIdx.x;
  if (i >= n4) return;
  float4 v = in[i];
  ushort4 o;
  o.x = f2bf(v.x); o.y = f2bf(v.y); o.z = f2bf(v.z); o.w = f2bf(v.w);
  out[i] = o;
}

// ---------------- fp32 [R][C] -> bf16 [C][R] transpose-cast ----------------
__global__ __launch_bounds__(256) void transpose_cast_kernel(const float* __restrict__ in,
                                                             u16* __restrict__ out, int R, int C) {
  __shared__ float tile[32][33];
  int bx = blockIdx.x * 32;
  int by = blockIdx.y * 32;
  int tx = threadIdx.x & 31, ty = threadIdx.x >> 5;
  for (int i = ty; i < 32; i += 8)
    tile[i][tx] = in[(size_t)(by + i) * C + bx + tx];
  __syncthreads();
  for (int i = ty; i < 32; i += 8)
    out[(size_t)(bx + i) * R + by + tx] = f2bf(tile[tx][i]);
}

// ---------------- bf16 MFMA GEMM (m97 structure): C = A * Bt^T + bias ----------------
// 128x128 tile, BK=32, 256 threads, global_load_lds width-16 staging
__global__ __launch_bounds__(256) void gemm_bt_kernel(const u16* __restrict__ A,
                                                      const u16* __restrict__ Bt,
                                                      const float* __restrict__ bias,
                                                      float* __restrict__ C,
                                                      int M, int N, int K) {
  __shared__ u16 sA[128 * 32];
  __shared__ u16 sB[128 * 32];
  const int tid  = threadIdx.x;
  const int lane = tid & 63, wave = tid >> 6;
  const int quad = lane >> 4, l16 = lane & 15;
  const int wm = (wave >> 1) * 64, wn = (wave & 1) * 64;
  const int bm = blockIdx.y, bn = blockIdx.x;

  const u16* gA0 = A  + (size_t)(bm * 128 + (tid >> 2)) * K + (tid & 3) * 8;
  const u16* gA1 = gA0 + (size_t)64 * K;
  const u16* gB0 = Bt + (size_t)(bn * 128 + (tid >> 2)) * K + (tid & 3) * 8;
  const u16* gB1 = gB0 + (size_t)64 * K;
  u16* lA0 = &sA[(size_t)tid * 8];
  u16* lA1 = &sA[(size_t)(256 + tid) * 8];
  u16* lB0 = &sB[(size_t)tid * 8];
  u16* lB1 = &sB[(size_t)(256 + tid) * 8];

  f32x4 acc[4][4] = {};

  for (int kt = 0; kt < K; kt += 32) {
    __syncthreads();   // previous iteration's LDS reads are done
    async_copy16(gA0 + kt, lA0);
    async_copy16(gA1 + kt, lA1);
    async_copy16(gB0 + kt, lB0);
    async_copy16(gB1 + kt, lB1);
    __syncthreads();   // drains vmcnt: staging visible

    bf16x8 af[4], bfr[4];
#pragma unroll
    for (int i = 0; i < 4; ++i)
      af[i] = *(const bf16x8*)&sA[(wm + i * 16 + l16) * 32 + quad * 8];
#pragma unroll
    for (int j = 0; j < 4; ++j)
      bfr[j] = *(const bf16x8*)&sB[(wn + j * 16 + l16) * 32 + quad * 8];
#pragma unroll
    for (int i = 0; i < 4; ++i)
#pragma unroll
      for (int j = 0; j < 4; ++j)
        acc[i][j] = __builtin_amdgcn_mfma_f32_16x16x32_bf16(af[i], bfr[j], acc[i][j], 0, 0, 0);
  }

#pragma unroll
  for (int i = 0; i < 4; ++i) {
    int row0 = bm * 128 + wm + i * 16 + quad * 4;
#pragma unroll
    for (int j = 0; j < 4; ++j) {
      int col = bn * 128 + wn + j * 16 + l16;
      float bi = bias[col];
#pragma unroll
      for (int r = 0; r < 4; ++r)
        C[(size_t)(row0 + r) * N + col] = acc[i][j][r] + bi;
    }
  }
}

// ---------------- RoPE + cast + layout for Q,K (bf16), scale folded into Q ----------------
__global__ __launch_bounds__(256) void qk_rope_cast_kernel(const float* __restrict__ qkv,
                                                           const int* __restrict__ pos,
                                                           u16* __restrict__ Qb,
                                                           u16* __restrict__ Kb) {
  int idx = blockIdx.x * 256 + threadIdx.x;   // T * 40 heads * 64 pairs
  int t = idx / 2560;
  int rem = idx - t * 2560;
  int head = rem >> 6, i = rem & 63;
  int b = t >> 11, s = t & 2047;
  float p = (float)pos[t];
  float inv = exp2f(-(float)i * 0.25952563f);   // (1e5)^(-2i/128)
  float f = p * inv;
  float sn, cs;
  sincosf(f, &sn, &cs);
  if (head < NH) {
    const float* src = qkv + (size_t)t * QKV_N + head * HD;
    float x1 = src[i], x2 = src[i + 64];
    u16* dst = Qb + (((size_t)(b * NH + head)) * S_LEN + s) * HD;
    dst[i]      = f2bf((x1 * cs - x2 * sn) * SCALE_F);
    dst[i + 64] = f2bf((x2 * cs + x1 * sn) * SCALE_F);
  } else {
    int kh = head - NH;
    const float* src = qkv + (size_t)t * QKV_N + QSZ + kh * HD;
    float x1 = src[i], x2 = src[i + 64];
    u16* dst = Kb + (((size_t)(b * NKV + kh)) * S_LEN + s) * HD;
    dst[i]      = f2bf(x1 * cs - x2 * sn);
    dst[i + 64] = f2bf(x2 * cs + x1 * sn);
  }
}

// ---------------- V transpose-cast: fp32 qkv -> bf16 Vtb [b][kvh][d=128][s=2048] ----------------
__global__ __launch_bounds__(256) void v_transpose_cast_kernel(const float* __restrict__ qkv,
                                                               u16* __restrict__ Vtb) {
  __shared__ float tile[32][33];
  int st = blockIdx.x * 32;
  int dt = blockIdx.y * 32;
  int bk = blockIdx.z;                      // b*8 + kvh
  int b = bk >> 3, kvh = bk & 7;
  int tx = threadIdx.x & 31, ty = threadIdx.x >> 5;
  const float* src = qkv + (size_t)(b * S_LEN) * QKV_N + QSZ + KVSZ + kvh * HD;
  for (int i = ty; i < 32; i += 8)
    tile[i][tx] = src[(size_t)(st + i) * QKV_N + dt + tx];
  __syncthreads();
  u16* dst = Vtb + (size_t)bk * HD * S_LEN;
  for (int i = ty; i < 32; i += 8)
    dst[(size_t)(dt + i) * S_LEN + st + tx] = f2bf(tile[tx][i]);
}

// ---------------- MFMA flash attention (causal, GQA 4:1) ----------------
// Swapped-operand structure: QK^T computed as mfma(K, Q) -> S^T (lane = q-row,
// k-index in registers) => in-lane softmax (2 cross-quad shuffles, per-lane m/l);
// PV computed as mfma(Vt, P) -> O^T (per-lane alpha rescale, no broadcasts).
// All LDS tiles XOR-swizzled ((row&7)<<3 on u16 index); 40 KB LDS -> 4 blocks/CU.
__global__ __launch_bounds__(256, 4) void flash_mfma_kernel(const u16* __restrict__ Qb,
                                                            const u16* __restrict__ Kb,
                                                            const u16* __restrict__ Vtb,
                                                            u16* __restrict__ attn) {
  const int qti = gridDim.x - 1 - blockIdx.x;   // long blocks launch first
  const int h = blockIdx.y, b = blockIdx.z;
  const int kvh = h >> 2;
  const int tid = threadIdx.x;
  const int lane = tid & 63, wave = tid >> 6;
  const int quad = lane >> 4, l16 = lane & 15;

  __shared__ u16 sK[64 * 128];     // [k-row][d]  swizzled, 16 KB
  __shared__ u16 sVt[128 * 64];    // [d][s]      swizzled, 16 KB
  __shared__ u16 sP[4][16 * 64];   // per-wave [q][k] swizzled, 8 KB

  // Q fragment (B-operand): lane l16 = q-row, elems = d-chunk quad*8+j
  bf16x8 qf[4];
  {
    const u16* qrow = Qb + (((size_t)(b * NH + h)) * S_LEN + (size_t)qti * 64 + wave * 16 + l16) * HD;
#pragma unroll
    for (int kc = 0; kc < 4; ++kc)
      qf[kc] = *(const bf16x8*)(qrow + kc * 32 + quad * 8);
  }

  f32x4 acc[8] = {};       // O^T: col l16 = q, rows quad*4+r = d within db*16
  float m_r = -INFINITY;   // per-lane running max for row q = l16
  float l_r = 0.f;

  const u16* Kbase = Kb  + ((size_t)(b * NKV + kvh)) * S_LEN * HD;
  const u16* Vbase = Vtb + ((size_t)(b * NKV + kvh)) * HD * S_LEN;

  // register prefetch buffers for next K/V tile
  u16x8 kv[4], vv[4];
#pragma unroll
  for (int i = 0; i < 4; ++i) {
    int c = i * 256 + tid;
    kv[i] = *(const u16x8*)(Kbase + (size_t)(c >> 4) * HD + (c & 15) * 8);
    vv[i] = *(const u16x8*)(Vbase + (size_t)(c >> 3) * S_LEN + (c & 7) * 8);
  }

  for (int kt = 0; kt <= qti; ++kt) {
    __syncthreads();   // previous compute done, LDS reusable
#pragma unroll
    for (int i = 0; i < 4; ++i) {
      int c = i * 256 + tid;
      int kr = c >> 4;
      *(u16x8*)&sK[(kr * 128 + (c & 15) * 8) ^ ((kr & 7) << 3)] = kv[i];
      int vr = c >> 3;
      *(u16x8*)&sVt[(vr * 64 + (c & 7) * 8) ^ ((vr & 7) << 3)] = vv[i];
    }
    __syncthreads();   // staging visible

    if (kt < qti) {    // prefetch next tile; vmcnt wait lands at next iter's LDS write
#pragma unroll
      for (int i = 0; i < 4; ++i) {
        int c = i * 256 + tid;
        kv[i] = *(const u16x8*)(Kbase + (size_t)((kt + 1) * 64 + (c >> 4)) * HD + (c & 15) * 8);
        vv[i] = *(const u16x8*)(Vbase + (size_t)(c >> 3) * S_LEN + (kt + 1) * 64 + (c & 7) * 8);
      }
    }

    // QK^T swapped: S^T[k][q] — A = K-frag (m = k-row), B = Q-frag (n = q-row)
    f32x4 s[4] = {};
#pragma unroll
    for (int kc = 0; kc < 4; ++kc) {
#pragma unroll
      for (int nb = 0; nb < 4; ++nb) {
        bf16x8 kf = *(const bf16x8*)&sK[((nb * 16 + l16) * 128 + kc * 32 + quad * 8) ^ ((l16 & 7) << 3)];
        s[nb] = __builtin_amdgcn_mfma_f32_16x16x32_bf16(kf, qf[kc], s[nb], 0, 0, 0);
      }
    }

    if (kt == qti) {   // causal mask on diagonal tile: k_local > q_local
      int qloc = wave * 16 + l16;
#pragma unroll
      for (int nb = 0; nb < 4; ++nb)
#pragma unroll
        for (int r = 0; r < 4; ++r)
          if (nb * 16 + quad * 4 + r > qloc) s[nb][r] = -1e30f;
    }

    // online softmax: lane owns row q = l16 (k-values split across quads)
    float mx = -1e30f;
#pragma unroll
    for (int nb = 0; nb < 4; ++nb)
#pragma unroll
      for (int r = 0; r < 4; ++r)
        mx = fmaxf(mx, s[nb][r]);
    mx = fmaxf(mx, __shfl_xor(mx, 16));
    mx = fmaxf(mx, __shfl_xor(mx, 32));
    float mnew = fmaxf(m_r, mx);
    float alpha = __expf(m_r - mnew);
    m_r = mnew;
    float rs = 0.f;
#pragma unroll
    for (int nb = 0; nb < 4; ++nb)
#pragma unroll
      for (int r = 0; r < 4; ++r) {
        float p = __expf(s[nb][r] - mnew);
        s[nb][r] = p;
        rs += p;
      }
    rs += __shfl_xor(rs, 16);
    rs += __shfl_xor(rs, 32);
    l_r = l_r * alpha + rs;

#pragma unroll
    for (int db = 0; db < 8; ++db)
#pragma unroll
      for (int r = 0; r < 4; ++r)
        acc[db][r] *= alpha;

    // P -> LDS: per lane 4x ds_write_b64, wave-private, swizzled
    u16* sPw = sP[wave];
#pragma unroll
    for (int nb = 0; nb < 4; ++nb) {
      u16x4 pk;
#pragma unroll
      for (int r = 0; r < 4; ++r) pk[r] = f2bf(s[nb][r]);
      *(u16x4*)&sPw[(l16 * 64 + nb * 16 + quad * 4) ^ ((l16 & 7) << 3)] = pk;
    }

    // PV swapped: O^T += V^T * P^T — A = Vt-frag (m = d), B = P-frag (n = q)
#pragma unroll
    for (int ch = 0; ch < 2; ++ch) {
      bf16x8 pf = *(const bf16x8*)&sPw[(l16 * 64 + ch * 32 + quad * 8) ^ ((l16 & 7) << 3)];
#pragma unroll
      for (int db = 0; db < 8; ++db) {
        bf16x8 vf = *(const bf16x8*)&sVt[((db * 16 + l16) * 64 + ch * 32 + quad * 8) ^ ((l16 & 7) << 3)];
        acc[db] = __builtin_amdgcn_mfma_f32_16x16x32_bf16(vf, pf, acc[db], 0, 0, 0);
      }
    }
  }

  // epilogue: normalize (per-lane), transpose via LDS (reuse sK), coalesced store
  float invl = 1.0f / l_r;
  __syncthreads();   // all waves done with sK/sVt reads
  u16* sOw = &sK[wave * 2048];   // per-wave [16 q][128 d] bf16, swizzled
#pragma unroll
  for (int db = 0; db < 8; ++db) {
    u16x4 pk;
#pragma unroll
    for (int r = 0; r < 4; ++r) pk[r] = f2bf(acc[db][r] * invl);
    *(u16x4*)&sOw[(l16 * 128 + db * 16 + quad * 4) ^ ((l16 & 7) << 3)] = pk;
  }
  // wave-private region: no barrier needed between write and read
#pragma unroll
  for (int p = 0; p < 4; ++p) {
    int row = p * 4 + quad;
    u16x8 o = *(const u16x8*)&sOw[(row * 128 + l16 * 8) ^ ((row & 7) << 3)];
    int q = qti * 64 + wave * 16 + row;
    *(u16x8*)(attn + ((size_t)(b * S_LEN + q)) * QSZ + (size_t)h * HD + l16 * 8) = o;
  }
}

extern "C" void kernel_launch(void* const* d_in, const int* in_sizes, int n_in,
                              void* d_out, int out_size, void* d_ws, size_t ws_size,
                              hipStream_t stream) {
  const float* hidden    = (const float*)d_in[0];
  const int*   positions = (const int*)d_in[1];
  const float* w_qkv     = (const float*)d_in[2];
  const float* b_qkv     = (const float*)d_in[3];
  const float* w_o       = (const float*)d_in[4];
  const float* b_o       = (const float*)d_in[5];
  float* out = (float*)d_out;

  char* ws = (char*)d_ws;
  const size_t MB = 1024 * 1024;
  u16*   hb    = (u16*)ws;                       // 0..32 MB   (gemm1 A)
  u16*   wqT   = (u16*)(ws + 32  * MB);          // 32..80 MB  (gemm1 B)
  u16*   woT   = (u16*)(ws + 80  * MB);          // 80..112 MB (gemm2 B)
  float* qkv   = (float*)(ws + 112 * MB);        // 112..208 MB
  u16*   attnb = (u16*)(ws + 208 * MB);          // 208..240 MB
  // overlays — alive only after gemm1 has consumed hb/wqT:
  u16*   Qb    = (u16*)ws;                       // 0..32 MB
  u16*   Kb    = (u16*)(ws + 32 * MB);           // 32..40 MB
  u16*   Vtb   = (u16*)(ws + 40 * MB);           // 40..48 MB

  cast_bf16_kernel<<<T_TOTAL * HIDDEN / 4 / 256, 256, 0, stream>>>(
      (const float4*)hidden, (ushort4*)hb, T_TOTAL * HIDDEN / 4);
  transpose_cast_kernel<<<dim3(QKV_N / 32, HIDDEN / 32), 256, 0, stream>>>(w_qkv, wqT, HIDDEN, QKV_N);
  transpose_cast_kernel<<<dim3(HIDDEN / 32, QSZ / 32), 256, 0, stream>>>(w_o, woT, QSZ, HIDDEN);
  gemm_bt_kernel<<<dim3(QKV_N / 128, T_TOTAL / 128), 256, 0, stream>>>(
      hb, wqT, b_qkv, qkv, T_TOTAL, QKV_N, HIDDEN);
  qk_rope_cast_kernel<<<T_TOTAL * 2560 / 256, 256, 0, stream>>>(qkv, positions, Qb, Kb);
  v_transpose_cast_kernel<<<dim3(S_LEN / 32, HD / 32, 16), 256, 0, stream>>>(qkv, Vtb);
  flash_mfma_kernel<<<dim3(S_LEN / 64, NH, 2), 256, 0, stream>>>(Qb, Kb, Vtb, attnb);
  gemm_bt_kernel<<<dim3(HIDDEN / 128, T_TOTAL / 128), 256, 0, stream>>>(
      attnb, woT, b_o, out, T_TOTAL, HIDDEN, QSZ);
}

// Round 2
// 1020.456 us; speedup vs baseline: 1.5063x; 1.5063x over previous
//
#include <hip/hip_runtime.h>
#include <cstdint>
#include <math.h>

#define T_TOTAL 4096
#define S_LEN   2048
#define NH      32
#define NKV     8
#define HD      128
#define HIDDEN  4096
#define QSZ     4096
#define KVSZ    1024
#define QKV_N   6144
#define SCALE_F 0.08838834764831843f   // 128^-0.5

typedef __bf16 bf16x8 __attribute__((ext_vector_type(8)));
typedef float  f32x4  __attribute__((ext_vector_type(4)));
typedef unsigned short u16;
typedef unsigned int   u32;
typedef u16 u16x8 __attribute__((ext_vector_type(8)));
typedef u16 u16x4 __attribute__((ext_vector_type(4)));

__device__ __forceinline__ u16 f2bf(float f) {
  u32 b = __float_as_uint(f);
  b += 0x7FFFu + ((b >> 16) & 1u);      // round-to-nearest-even
  return (u16)(b >> 16);
}

// async global->LDS, 16B per lane; LDS dst MUST be uniform base + lane*16
__device__ __forceinline__ void async_copy16(const u16* g, u16* l) {
  __builtin_amdgcn_global_load_lds(
      (const __attribute__((address_space(1))) void*)(g),
      (__attribute__((address_space(3))) void*)(l), 16, 0, 0);
}

// ---------------- fp32 -> bf16 cast (vectorized) ----------------
__global__ __launch_bounds__(256) void cast_bf16_kernel(const float4* __restrict__ in,
                                                        ushort4* __restrict__ out, int n4) {
  int i = blockIdx.x * 256 + threadIdx.x;
  if (i >= n4) return;
  float4 v = in[i];
  ushort4 o;
  o.x = f2bf(v.x); o.y = f2bf(v.y); o.z = f2bf(v.z); o.w = f2bf(v.w);
  out[i] = o;
}

// ---------------- fp32 [R][C] -> bf16 [C][R] transpose-cast ----------------
__global__ __launch_bounds__(256) void transpose_cast_kernel(const float* __restrict__ in,
                                                             u16* __restrict__ out, int R, int C) {
  __shared__ float tile[32][33];
  int bx = blockIdx.x * 32;
  int by = blockIdx.y * 32;
  int tx = threadIdx.x & 31, ty = threadIdx.x >> 5;
  for (int i = ty; i < 32; i += 8)
    tile[i][tx] = in[(size_t)(by + i) * C + bx + tx];
  __syncthreads();
  for (int i = ty; i < 32; i += 8)
    out[(size_t)(bx + i) * R + by + tx] = f2bf(tile[tx][i]);
}

// ---------------- bf16 MFMA GEMM (m97 structure): C = A * Bt^T + bias ----------------
// 128x128 tile, BK=32, 256 threads, global_load_lds width-16 staging
__global__ __launch_bounds__(256) void gemm_bt_kernel(const u16* __restrict__ A,
                                                      const u16* __restrict__ Bt,
                                                      const float* __restrict__ bias,
                                                      float* __restrict__ C,
                                                      int M, int N, int K) {
  __shared__ u16 sA[128 * 32];
  __shared__ u16 sB[128 * 32];
  const int tid  = threadIdx.x;
  const int lane = tid & 63, wave = tid >> 6;
  const int quad = lane >> 4, l16 = lane & 15;
  const int wm = (wave >> 1) * 64, wn = (wave & 1) * 64;
  const int bm = blockIdx.y, bn = blockIdx.x;

  const u16* gA0 = A  + (size_t)(bm * 128 + (tid >> 2)) * K + (tid & 3) * 8;
  const u16* gA1 = gA0 + (size_t)64 * K;
  const u16* gB0 = Bt + (size_t)(bn * 128 + (tid >> 2)) * K + (tid & 3) * 8;
  const u16* gB1 = gB0 + (size_t)64 * K;
  u16* lA0 = &sA[(size_t)tid * 8];
  u16* lA1 = &sA[(size_t)(256 + tid) * 8];
  u16* lB0 = &sB[(size_t)tid * 8];
  u16* lB1 = &sB[(size_t)(256 + tid) * 8];

  f32x4 acc[4][4] = {};

  for (int kt = 0; kt < K; kt += 32) {
    __syncthreads();   // previous iteration's LDS reads are done
    async_copy16(gA0 + kt, lA0);
    async_copy16(gA1 + kt, lA1);
    async_copy16(gB0 + kt, lB0);
    async_copy16(gB1 + kt, lB1);
    __syncthreads();   // drains vmcnt: staging visible

    bf16x8 af[4], bfr[4];
#pragma unroll
    for (int i = 0; i < 4; ++i)
      af[i] = *(const bf16x8*)&sA[(wm + i * 16 + l16) * 32 + quad * 8];
#pragma unroll
    for (int j = 0; j < 4; ++j)
      bfr[j] = *(const bf16x8*)&sB[(wn + j * 16 + l16) * 32 + quad * 8];
#pragma unroll
    for (int i = 0; i < 4; ++i)
#pragma unroll
      for (int j = 0; j < 4; ++j)
        acc[i][j] = __builtin_amdgcn_mfma_f32_16x16x32_bf16(af[i], bfr[j], acc[i][j], 0, 0, 0);
  }

#pragma unroll
  for (int i = 0; i < 4; ++i) {
    int row0 = bm * 128 + wm + i * 16 + quad * 4;
#pragma unroll
    for (int j = 0; j < 4; ++j) {
      int col = bn * 128 + wn + j * 16 + l16;
      float bi = bias[col];
#pragma unroll
      for (int r = 0; r < 4; ++r)
        C[(size_t)(row0 + r) * N + col] = acc[i][j][r] + bi;
    }
  }
}

// ---------------- RoPE + cast + layout for Q,K (bf16), scale folded into Q ----------------
__global__ __launch_bounds__(256) void qk_rope_cast_kernel(const float* __restrict__ qkv,
                                                           const int* __restrict__ pos,
                                                           u16* __restrict__ Qb,
                                                           u16* __restrict__ Kb) {
  int idx = blockIdx.x * 256 + threadIdx.x;   // T * 40 heads * 64 pairs
  int t = idx / 2560;
  int rem = idx - t * 2560;
  int head = rem >> 6, i = rem & 63;
  int b = t >> 11, s = t & 2047;
  float p = (float)pos[t];
  float inv = exp2f(-(float)i * 0.25952563f);   // (1e5)^(-2i/128)
  float f = p * inv;
  float sn, cs;
  sincosf(f, &sn, &cs);
  if (head < NH) {
    const float* src = qkv + (size_t)t * QKV_N + head * HD;
    float x1 = src[i], x2 = src[i + 64];
    u16* dst = Qb + (((size_t)(b * NH + head)) * S_LEN + s) * HD;
    dst[i]      = f2bf((x1 * cs - x2 * sn) * SCALE_F);
    dst[i + 64] = f2bf((x2 * cs + x1 * sn) * SCALE_F);
  } else {
    int kh = head - NH;
    const float* src = qkv + (size_t)t * QKV_N + QSZ + kh * HD;
    float x1 = src[i], x2 = src[i + 64];
    u16* dst = Kb + (((size_t)(b * NKV + kh)) * S_LEN + s) * HD;
    dst[i]      = f2bf(x1 * cs - x2 * sn);
    dst[i + 64] = f2bf(x2 * cs + x1 * sn);
  }
}

// ---------------- V transpose-cast: fp32 qkv -> bf16 Vtb [b][kvh][d=128][s=2048] ----------------
__global__ __launch_bounds__(256) void v_transpose_cast_kernel(const float* __restrict__ qkv,
                                                               u16* __restrict__ Vtb) {
  __shared__ float tile[32][33];
  int st = blockIdx.x * 32;
  int dt = blockIdx.y * 32;
  int bk = blockIdx.z;                      // b*8 + kvh
  int b = bk >> 3, kvh = bk & 7;
  int tx = threadIdx.x & 31, ty = threadIdx.x >> 5;
  const float* src = qkv + (size_t)(b * S_LEN) * QKV_N + QSZ + KVSZ + kvh * HD;
  for (int i = ty; i < 32; i += 8)
    tile[i][tx] = src[(size_t)(st + i) * QKV_N + dt + tx];
  __syncthreads();
  u16* dst = Vtb + (size_t)bk * HD * S_LEN;
  for (int i = ty; i < 32; i += 8)
    dst[(size_t)(dt + i) * S_LEN + st + tx] = f2bf(tile[tx][i]);
}

// ---------------- MFMA flash attention (causal, GQA 4:1) ----------------
// Swapped-operand structure: QK^T computed as mfma(K, Q) -> S^T (lane = q-row,
// k-index in registers) => in-lane softmax (2 cross-quad shuffles, per-lane m/l);
// PV computed as mfma(Vt, P) -> O^T (per-lane alpha rescale, no broadcasts).
// All LDS tiles XOR-swizzled ((row&7)<<3 on u16 index); 40 KB LDS.
// NOTE: no min-waves hint — launch_bounds(256,4) forced VGPR=64 and spilled
// everything to scratch (FETCH_SIZE 75MB -> 632MB, 2.1x slowdown). With
// natural allocation (~100-110 VGPR <= 128) the 40KB LDS still gives 4 blocks/CU.
__global__ __launch_bounds__(256) void flash_mfma_kernel(const u16* __restrict__ Qb,
                                                         const u16* __restrict__ Kb,
                                                         const u16* __restrict__ Vtb,
                                                         u16* __restrict__ attn) {
  const int qti = gridDim.x - 1 - blockIdx.x;   // long blocks launch first
  const int h = blockIdx.y, b = blockIdx.z;
  const int kvh = h >> 2;
  const int tid = threadIdx.x;
  const int lane = tid & 63, wave = tid >> 6;
  const int quad = lane >> 4, l16 = lane & 15;

  __shared__ u16 sK[64 * 128];     // [k-row][d]  swizzled, 16 KB
  __shared__ u16 sVt[128 * 64];    // [d][s]      swizzled, 16 KB
  __shared__ u16 sP[4][16 * 64];   // per-wave [q][k] swizzled, 8 KB

  // Q fragment (B-operand): lane l16 = q-row, elems = d-chunk quad*8+j
  bf16x8 qf[4];
  {
    const u16* qrow = Qb + (((size_t)(b * NH + h)) * S_LEN + (size_t)qti * 64 + wave * 16 + l16) * HD;
#pragma unroll
    for (int kc = 0; kc < 4; ++kc)
      qf[kc] = *(const bf16x8*)(qrow + kc * 32 + quad * 8);
  }

  f32x4 acc[8] = {};       // O^T: col l16 = q, rows quad*4+r = d within db*16
  float m_r = -INFINITY;   // per-lane running max for row q = l16
  float l_r = 0.f;

  const u16* Kbase = Kb  + ((size_t)(b * NKV + kvh)) * S_LEN * HD;
  const u16* Vbase = Vtb + ((size_t)(b * NKV + kvh)) * HD * S_LEN;

  // register prefetch buffers for next K/V tile
  u16x8 kv[4], vv[4];
#pragma unroll
  for (int i = 0; i < 4; ++i) {
    int c = i * 256 + tid;
    kv[i] = *(const u16x8*)(Kbase + (size_t)(c >> 4) * HD + (c & 15) * 8);
    vv[i] = *(const u16x8*)(Vbase + (size_t)(c >> 3) * S_LEN + (c & 7) * 8);
  }

  for (int kt = 0; kt <= qti; ++kt) {
    __syncthreads();   // previous compute done, LDS reusable
#pragma unroll
    for (int i = 0; i < 4; ++i) {
      int c = i * 256 + tid;
      int kr = c >> 4;
      *(u16x8*)&sK[(kr * 128 + (c & 15) * 8) ^ ((kr & 7) << 3)] = kv[i];
      int vr = c >> 3;
      *(u16x8*)&sVt[(vr * 64 + (c & 7) * 8) ^ ((vr & 7) << 3)] = vv[i];
    }
    __syncthreads();   // staging visible

    if (kt < qti) {    // prefetch next tile; vmcnt wait lands at next iter's LDS write
#pragma unroll
      for (int i = 0; i < 4; ++i) {
        int c = i * 256 + tid;
        kv[i] = *(const u16x8*)(Kbase + (size_t)((kt + 1) * 64 + (c >> 4)) * HD + (c & 15) * 8);
        vv[i] = *(const u16x8*)(Vbase + (size_t)(c >> 3) * S_LEN + (kt + 1) * 64 + (c & 7) * 8);
      }
    }

    // QK^T swapped: S^T[k][q] — A = K-frag (m = k-row), B = Q-frag (n = q-row)
    f32x4 s[4] = {};
#pragma unroll
    for (int kc = 0; kc < 4; ++kc) {
#pragma unroll
      for (int nb = 0; nb < 4; ++nb) {
        bf16x8 kf = *(const bf16x8*)&sK[((nb * 16 + l16) * 128 + kc * 32 + quad * 8) ^ ((l16 & 7) << 3)];
        s[nb] = __builtin_amdgcn_mfma_f32_16x16x32_bf16(kf, qf[kc], s[nb], 0, 0, 0);
      }
    }

    if (kt == qti) {   // causal mask on diagonal tile: k_local > q_local
      int qloc = wave * 16 + l16;
#pragma unroll
      for (int nb = 0; nb < 4; ++nb)
#pragma unroll
        for (int r = 0; r < 4; ++r)
          if (nb * 16 + quad * 4 + r > qloc) s[nb][r] = -1e30f;
    }

    // online softmax: lane owns row q = l16 (k-values split across quads)
    float mx = -1e30f;
#pragma unroll
    for (int nb = 0; nb < 4; ++nb)
#pragma unroll
      for (int r = 0; r < 4; ++r)
        mx = fmaxf(mx, s[nb][r]);
    mx = fmaxf(mx, __shfl_xor(mx, 16));
    mx = fmaxf(mx, __shfl_xor(mx, 32));
    float mnew = fmaxf(m_r, mx);
    float alpha = __expf(m_r - mnew);
    m_r = mnew;
    float rs = 0.f;
#pragma unroll
    for (int nb = 0; nb < 4; ++nb)
#pragma unroll
      for (int r = 0; r < 4; ++r) {
        float p = __expf(s[nb][r] - mnew);
        s[nb][r] = p;
        rs += p;
      }
    rs += __shfl_xor(rs, 16);
    rs += __shfl_xor(rs, 32);
    l_r = l_r * alpha + rs;

#pragma unroll
    for (int db = 0; db < 8; ++db)
#pragma unroll
      for (int r = 0; r < 4; ++r)
        acc[db][r] *= alpha;

    // P -> LDS: per lane 4x ds_write_b64, wave-private, swizzled
    u16* sPw = sP[wave];
#pragma unroll
    for (int nb = 0; nb < 4; ++nb) {
      u16x4 pk;
#pragma unroll
      for (int r = 0; r < 4; ++r) pk[r] = f2bf(s[nb][r]);
      *(u16x4*)&sPw[(l16 * 64 + nb * 16 + quad * 4) ^ ((l16 & 7) << 3)] = pk;
    }

    // PV swapped: O^T += V^T * P^T — A = Vt-frag (m = d), B = P-frag (n = q)
#pragma unroll
    for (int ch = 0; ch < 2; ++ch) {
      bf16x8 pf = *(const bf16x8*)&sPw[(l16 * 64 + ch * 32 + quad * 8) ^ ((l16 & 7) << 3)];
#pragma unroll
      for (int db = 0; db < 8; ++db) {
        bf16x8 vf = *(const bf16x8*)&sVt[((db * 16 + l16) * 64 + ch * 32 + quad * 8) ^ ((l16 & 7) << 3)];
        acc[db] = __builtin_amdgcn_mfma_f32_16x16x32_bf16(vf, pf, acc[db], 0, 0, 0);
      }
    }
  }

  // epilogue: normalize (per-lane), transpose via LDS (reuse sK), coalesced store
  float invl = 1.0f / l_r;
  __syncthreads();   // all waves done with sK/sVt reads
  u16* sOw = &sK[wave * 2048];   // per-wave [16 q][128 d] bf16, swizzled
#pragma unroll
  for (int db = 0; db < 8; ++db) {
    u16x4 pk;
#pragma unroll
    for (int r = 0; r < 4; ++r) pk[r] = f2bf(acc[db][r] * invl);
    *(u16x4*)&sOw[(l16 * 128 + db * 16 + quad * 4) ^ ((l16 & 7) << 3)] = pk;
  }
  // wave-private region: no barrier needed between write and read
#pragma unroll
  for (int p = 0; p < 4; ++p) {
    int row = p * 4 + quad;
    u16x8 o = *(const u16x8*)&sOw[(row * 128 + l16 * 8) ^ ((row & 7) << 3)];
    int q = qti * 64 + wave * 16 + row;
    *(u16x8*)(attn + ((size_t)(b * S_LEN + q)) * QSZ + (size_t)h * HD + l16 * 8) = o;
  }
}

extern "C" void kernel_launch(void* const* d_in, const int* in_sizes, int n_in,
                              void* d_out, int out_size, void* d_ws, size_t ws_size,
                              hipStream_t stream) {
  const float* hidden    = (const float*)d_in[0];
  const int*   positions = (const int*)d_in[1];
  const float* w_qkv     = (const float*)d_in[2];
  const float* b_qkv     = (const float*)d_in[3];
  const float* w_o       = (const float*)d_in[4];
  const float* b_o       = (const float*)d_in[5];
  float* out = (float*)d_out;

  char* ws = (char*)d_ws;
  const size_t MB = 1024 * 1024;
  u16*   hb    = (u16*)ws;                       // 0..32 MB   (gemm1 A)
  u16*   wqT   = (u16*)(ws + 32  * MB);          // 32..80 MB  (gemm1 B)
  u16*   woT   = (u16*)(ws + 80  * MB);          // 80..112 MB (gemm2 B)
  float* qkv   = (float*)(ws + 112 * MB);        // 112..208 MB
  u16*   attnb = (u16*)(ws + 208 * MB);          // 208..240 MB
  // overlays — alive only after gemm1 has consumed hb/wqT:
  u16*   Qb    = (u16*)ws;                       // 0..32 MB
  u16*   Kb    = (u16*)(ws + 32 * MB);           // 32..40 MB
  u16*   Vtb   = (u16*)(ws + 40 * MB);           // 40..48 MB

  cast_bf16_kernel<<<T_TOTAL * HIDDEN / 4 / 256, 256, 0, stream>>>(
      (const float4*)hidden, (ushort4*)hb, T_TOTAL * HIDDEN / 4);
  transpose_cast_kernel<<<dim3(QKV_N / 32, HIDDEN / 32), 256, 0, stream>>>(w_qkv, wqT, HIDDEN, QKV_N);
  transpose_cast_kernel<<<dim3(HIDDEN / 32, QSZ / 32), 256, 0, stream>>>(w_o, woT, QSZ, HIDDEN);
  gemm_bt_kernel<<<dim3(QKV_N / 128, T_TOTAL / 128), 256, 0, stream>>>(
      hb, wqT, b_qkv, qkv, T_TOTAL, QKV_N, HIDDEN);
  qk_rope_cast_kernel<<<T_TOTAL * 2560 / 256, 256, 0, stream>>>(qkv, positions, Qb, Kb);
  v_transpose_cast_kernel<<<dim3(S_LEN / 32, HD / 32, 16), 256, 0, stream>>>(qkv, Vtb);
  flash_mfma_kernel<<<dim3(S_LEN / 64, NH, 2), 256, 0, stream>>>(Qb, Kb, Vtb, attnb);
  gemm_bt_kernel<<<dim3(HIDDEN / 128, T_TOTAL / 128), 256, 0, stream>>>(
      attnb, woT, b_o, out, T_TOTAL, HIDDEN, QSZ);
}

// Round 3
// 922.235 us; speedup vs baseline: 1.6667x; 1.1065x over previous
//
#include <hip/hip_runtime.h>
#include <cstdint>
#include <math.h>

#define T_TOTAL 4096
#define S_LEN   2048
#define NH      32
#define NKV     8
#define HD      128
#define HIDDEN  4096
#define QSZ     4096
#define KVSZ    1024
#define QKV_N   6144
#define SCALE_F 0.08838834764831843f   // 128^-0.5

typedef __bf16 bf16x8 __attribute__((ext_vector_type(8)));
typedef float  f32x4  __attribute__((ext_vector_type(4)));
typedef unsigned short u16;
typedef unsigned int   u32;
typedef u16 u16x8 __attribute__((ext_vector_type(8)));
typedef u16 u16x4 __attribute__((ext_vector_type(4)));

__device__ __forceinline__ u16 f2bf(float f) {
  u32 b = __float_as_uint(f);
  b += 0x7FFFu + ((b >> 16) & 1u);      // round-to-nearest-even
  return (u16)(b >> 16);
}

// async global->LDS, 16B per lane; LDS dst MUST be uniform base + lane*16
__device__ __forceinline__ void async_copy16(const u16* g, u16* l) {
  __builtin_amdgcn_global_load_lds(
      (const __attribute__((address_space(1))) void*)(g),
      (__attribute__((address_space(3))) void*)(l), 16, 0, 0);
}

// ---------------- fp32 -> bf16 cast (vectorized) ----------------
__global__ __launch_bounds__(256) void cast_bf16_kernel(const float4* __restrict__ in,
                                                        ushort4* __restrict__ out, int n4) {
  int i = blockIdx.x * 256 + threadIdx.x;
  if (i >= n4) return;
  float4 v = in[i];
  ushort4 o;
  o.x = f2bf(v.x); o.y = f2bf(v.y); o.z = f2bf(v.z); o.w = f2bf(v.w);
  out[i] = o;
}

// ---------------- fp32 [R][C] -> bf16 [C][R] transpose-cast ----------------
__global__ __launch_bounds__(256) void transpose_cast_kernel(const float* __restrict__ in,
                                                             u16* __restrict__ out, int R, int C) {
  __shared__ float tile[32][33];
  int bx = blockIdx.x * 32;
  int by = blockIdx.y * 32;
  int tx = threadIdx.x & 31, ty = threadIdx.x >> 5;
  for (int i = ty; i < 32; i += 8)
    tile[i][tx] = in[(size_t)(by + i) * C + bx + tx];
  __syncthreads();
  for (int i = ty; i < 32; i += 8)
    out[(size_t)(bx + i) * R + by + tx] = f2bf(tile[tx][i]);
}

// ---------------- pipelined bf16 MFMA GEMM: C = A * Bt^T + bias ----------------
// 256x256 tile, BK=32, 512 threads (8 waves as 2Mx4N), 3-slot LDS ring (96 KB),
// counted vmcnt (T4: never 0 in steady state), raw s_barrier (no implicit drain),
// XOR-swizzled LDS via pre-swizzled global source (rule 21), XCD-bijective swizzle (T1).
__global__ __launch_bounds__(512) void gemm_pipe_kernel(const u16* __restrict__ A,
                                                        const u16* __restrict__ Bt,
                                                        const float* __restrict__ bias,
                                                        float* __restrict__ C,
                                                        int M, int N, int K, int nbn) {
  __shared__ u16 lds[3][2][8192];   // [slot][A|B][256 rows x 32 k], 96 KB
  const int tid  = threadIdx.x;
  const int lane = tid & 63, wave = tid >> 6;
  const int quad = lane >> 4, l16 = lane & 15;
  const int wm = (wave >> 2) * 128;   // wave M-offset (2 rows of waves)
  const int wn = (wave & 3) * 64;     // wave N-offset (4 cols of waves)

  // XCD-aware bijective swizzle (both call sites: gridDim.x % 8 == 0)
  const int cpx = gridDim.x >> 3;
  const int logical = (blockIdx.x & 7) * cpx + (blockIdx.x >> 3);
  const int bm = logical / nbn, bn = logical % nbn;

  // Staging: thread t owns row = e*128 + (t>>2), 16B chunk (t&3) of the slot.
  // LDS dest is linear (gload_lds requirement); the XOR swizzle is carried by
  // the global source chunk: g = (t&3) ^ ((row>>1)&3) = (t&3) ^ ((t>>3)&3).
  const int trow = tid >> 2;
  const int gch  = ((tid & 3) ^ ((tid >> 3) & 3)) * 8;
  const u16* gA = A  + (size_t)(bm * 256 + trow) * K + gch;
  const u16* gB = Bt + (size_t)(bn * 256 + trow) * K + gch;
  const size_t eoff = (size_t)128 * K;

  const int NT = K >> 5;
  // prologue: stage K-tiles 0,1,2 into slots 0,1,2 (issue order = vmcnt order)
#pragma unroll
  for (int pt = 0; pt < 3; ++pt) {
    int kt = pt * 32;
    async_copy16(gA + kt,        &lds[pt][0][tid * 8]);
    async_copy16(gA + eoff + kt, &lds[pt][0][4096 + tid * 8]);
    async_copy16(gB + kt,        &lds[pt][1][tid * 8]);
    async_copy16(gB + eoff + kt, &lds[pt][1][4096 + tid * 8]);
  }

  // frag-read swizzled chunk: quad ^ ((row>>1)&3); row low bits come from l16
  const int sw = (quad ^ ((l16 >> 1) & 3)) * 8;
  f32x4 acc[8][4] = {};
  int sl = 0;
  for (int t = 0; t < NT; ++t) {
    int rem = NT - t;
    if (rem >= 3)      asm volatile("s_waitcnt vmcnt(8)" ::: "memory");  // tile t landed; t+1,t+2 in flight
    else if (rem == 2) asm volatile("s_waitcnt vmcnt(4)" ::: "memory");
    else               asm volatile("s_waitcnt vmcnt(0)" ::: "memory");
    __builtin_amdgcn_s_barrier();   // tile t visible to all waves

    const u16* sAt = lds[sl][0];
    const u16* sBt = lds[sl][1];
    bf16x8 af[8], bfr[4];
#pragma unroll
    for (int i = 0; i < 8; ++i)
      af[i] = *(const bf16x8*)&sAt[(wm + i * 16 + l16) * 32 + sw];
#pragma unroll
    for (int j = 0; j < 4; ++j)
      bfr[j] = *(const bf16x8*)&sBt[(wn + j * 16 + l16) * 32 + sw];
    asm volatile("s_waitcnt lgkmcnt(0)" ::: "memory");
    __builtin_amdgcn_s_barrier();   // all waves done reading slot sl

    if (t + 3 < NT) {               // restage the freed slot; loads fly across barriers
      int kt = (t + 3) * 32;
      async_copy16(gA + kt,        &lds[sl][0][tid * 8]);
      async_copy16(gA + eoff + kt, &lds[sl][0][4096 + tid * 8]);
      async_copy16(gB + kt,        &lds[sl][1][tid * 8]);
      async_copy16(gB + eoff + kt, &lds[sl][1][4096 + tid * 8]);
    }

#pragma unroll
    for (int i = 0; i < 8; ++i)
#pragma unroll
      for (int j = 0; j < 4; ++j)
        acc[i][j] = __builtin_amdgcn_mfma_f32_16x16x32_bf16(af[i], bfr[j], acc[i][j], 0, 0, 0);
    sl = (sl == 2) ? 0 : sl + 1;
  }

  // epilogue: bias + fp32 store (C row = bm*256+wm+i*16+quad*4+r, col = bn*256+wn+j*16+l16)
#pragma unroll
  for (int i = 0; i < 8; ++i) {
    int row0 = bm * 256 + wm + i * 16 + quad * 4;
#pragma unroll
    for (int j = 0; j < 4; ++j) {
      int col = bn * 256 + wn + j * 16 + l16;
      float bi = bias[col];
#pragma unroll
      for (int r = 0; r < 4; ++r)
        C[(size_t)(row0 + r) * N + col] = acc[i][j][r] + bi;
    }
  }
}

// ---------------- RoPE + cast + layout for Q,K (bf16), scale folded into Q ----------------
__global__ __launch_bounds__(256) void qk_rope_cast_kernel(const float* __restrict__ qkv,
                                                           const int* __restrict__ pos,
                                                           u16* __restrict__ Qb,
                                                           u16* __restrict__ Kb) {
  int idx = blockIdx.x * 256 + threadIdx.x;   // T * 40 heads * 64 pairs
  int t = idx / 2560;
  int rem = idx - t * 2560;
  int head = rem >> 6, i = rem & 63;
  int b = t >> 11, s = t & 2047;
  float p = (float)pos[t];
  float inv = exp2f(-(float)i * 0.25952563f);   // (1e5)^(-2i/128)
  float f = p * inv;
  float sn, cs;
  sincosf(f, &sn, &cs);
  if (head < NH) {
    const float* src = qkv + (size_t)t * QKV_N + head * HD;
    float x1 = src[i], x2 = src[i + 64];
    u16* dst = Qb + (((size_t)(b * NH + head)) * S_LEN + s) * HD;
    dst[i]      = f2bf((x1 * cs - x2 * sn) * SCALE_F);
    dst[i + 64] = f2bf((x2 * cs + x1 * sn) * SCALE_F);
  } else {
    int kh = head - NH;
    const float* src = qkv + (size_t)t * QKV_N + QSZ + kh * HD;
    float x1 = src[i], x2 = src[i + 64];
    u16* dst = Kb + (((size_t)(b * NKV + kh)) * S_LEN + s) * HD;
    dst[i]      = f2bf(x1 * cs - x2 * sn);
    dst[i + 64] = f2bf(x2 * cs + x1 * sn);
  }
}

// ---------------- V transpose-cast: fp32 qkv -> bf16 Vtb [b][kvh][d=128][s=2048] ----------------
__global__ __launch_bounds__(256) void v_transpose_cast_kernel(const float* __restrict__ qkv,
                                                               u16* __restrict__ Vtb) {
  __shared__ float tile[32][33];
  int st = blockIdx.x * 32;
  int dt = blockIdx.y * 32;
  int bk = blockIdx.z;                      // b*8 + kvh
  int b = bk >> 3, kvh = bk & 7;
  int tx = threadIdx.x & 31, ty = threadIdx.x >> 5;
  const float* src = qkv + (size_t)(b * S_LEN) * QKV_N + QSZ + KVSZ + kvh * HD;
  for (int i = ty; i < 32; i += 8)
    tile[i][tx] = src[(size_t)(st + i) * QKV_N + dt + tx];
  __syncthreads();
  u16* dst = Vtb + (size_t)bk * HD * S_LEN;
  for (int i = ty; i < 32; i += 8)
    dst[(size_t)(dt + i) * S_LEN + st + tx] = f2bf(tile[tx][i]);
}

// ---------------- MFMA flash attention (causal, GQA 4:1) ----------------
// Swapped-operand structure: QK^T computed as mfma(K, Q) -> S^T (lane = q-row,
// k-index in registers) => in-lane softmax (2 cross-quad shuffles, per-lane m/l);
// PV computed as mfma(Vt, P) -> O^T (per-lane alpha rescale, no broadcasts).
// All LDS tiles XOR-swizzled ((row&7)<<3 on u16 index); 40 KB LDS.
// NOTE: no min-waves hint — launch_bounds(256,4) forced VGPR=64 and spilled
// everything to scratch (FETCH_SIZE 75MB -> 632MB, 2.1x slowdown). With
// natural allocation (~100-110 VGPR <= 128) the 40KB LDS still gives 4 blocks/CU.
__global__ __launch_bounds__(256) void flash_mfma_kernel(const u16* __restrict__ Qb,
                                                         const u16* __restrict__ Kb,
                                                         const u16* __restrict__ Vtb,
                                                         u16* __restrict__ attn) {
  const int qti = gridDim.x - 1 - blockIdx.x;   // long blocks launch first
  const int h = blockIdx.y, b = blockIdx.z;
  const int kvh = h >> 2;
  const int tid = threadIdx.x;
  const int lane = tid & 63, wave = tid >> 6;
  const int quad = lane >> 4, l16 = lane & 15;

  __shared__ u16 sK[64 * 128];     // [k-row][d]  swizzled, 16 KB
  __shared__ u16 sVt[128 * 64];    // [d][s]      swizzled, 16 KB
  __shared__ u16 sP[4][16 * 64];   // per-wave [q][k] swizzled, 8 KB

  // Q fragment (B-operand): lane l16 = q-row, elems = d-chunk quad*8+j
  bf16x8 qf[4];
  {
    const u16* qrow = Qb + (((size_t)(b * NH + h)) * S_LEN + (size_t)qti * 64 + wave * 16 + l16) * HD;
#pragma unroll
    for (int kc = 0; kc < 4; ++kc)
      qf[kc] = *(const bf16x8*)(qrow + kc * 32 + quad * 8);
  }

  f32x4 acc[8] = {};       // O^T: col l16 = q, rows quad*4+r = d within db*16
  float m_r = -INFINITY;   // per-lane running max for row q = l16
  float l_r = 0.f;

  const u16* Kbase = Kb  + ((size_t)(b * NKV + kvh)) * S_LEN * HD;
  const u16* Vbase = Vtb + ((size_t)(b * NKV + kvh)) * HD * S_LEN;

  // register prefetch buffers for next K/V tile
  u16x8 kv[4], vv[4];
#pragma unroll
  for (int i = 0; i < 4; ++i) {
    int c = i * 256 + tid;
    kv[i] = *(const u16x8*)(Kbase + (size_t)(c >> 4) * HD + (c & 15) * 8);
    vv[i] = *(const u16x8*)(Vbase + (size_t)(c >> 3) * S_LEN + (c & 7) * 8);
  }

  for (int kt = 0; kt <= qti; ++kt) {
    __syncthreads();   // previous compute done, LDS reusable
#pragma unroll
    for (int i = 0; i < 4; ++i) {
      int c = i * 256 + tid;
      int kr = c >> 4;
      *(u16x8*)&sK[(kr * 128 + (c & 15) * 8) ^ ((kr & 7) << 3)] = kv[i];
      int vr = c >> 3;
      *(u16x8*)&sVt[(vr * 64 + (c & 7) * 8) ^ ((vr & 7) << 3)] = vv[i];
    }
    __syncthreads();   // staging visible

    if (kt < qti) {    // prefetch next tile; vmcnt wait lands at next iter's LDS write
#pragma unroll
      for (int i = 0; i < 4; ++i) {
        int c = i * 256 + tid;
        kv[i] = *(const u16x8*)(Kbase + (size_t)((kt + 1) * 64 + (c >> 4)) * HD + (c & 15) * 8);
        vv[i] = *(const u16x8*)(Vbase + (size_t)(c >> 3) * S_LEN + (kt + 1) * 64 + (c & 7) * 8);
      }
    }

    // QK^T swapped: S^T[k][q] — A = K-frag (m = k-row), B = Q-frag (n = q-row)
    f32x4 s[4] = {};
#pragma unroll
    for (int kc = 0; kc < 4; ++kc) {
#pragma unroll
      for (int nb = 0; nb < 4; ++nb) {
        bf16x8 kf = *(const bf16x8*)&sK[((nb * 16 + l16) * 128 + kc * 32 + quad * 8) ^ ((l16 & 7) << 3)];
        s[nb] = __builtin_amdgcn_mfma_f32_16x16x32_bf16(kf, qf[kc], s[nb], 0, 0, 0);
      }
    }

    if (kt == qti) {   // causal mask on diagonal tile: k_local > q_local
      int qloc = wave * 16 + l16;
#pragma unroll
      for (int nb = 0; nb < 4; ++nb)
#pragma unroll
        for (int r = 0; r < 4; ++r)
          if (nb * 16 + quad * 4 + r > qloc) s[nb][r] = -1e30f;
    }

    // online softmax: lane owns row q = l16 (k-values split across quads)
    float mx = -1e30f;
#pragma unroll
    for (int nb = 0; nb < 4; ++nb)
#pragma unroll
      for (int r = 0; r < 4; ++r)
        mx = fmaxf(mx, s[nb][r]);
    mx = fmaxf(mx, __shfl_xor(mx, 16));
    mx = fmaxf(mx, __shfl_xor(mx, 32));
    float mnew = fmaxf(m_r, mx);
    float alpha = __expf(m_r - mnew);
    m_r = mnew;
    float rs = 0.f;
#pragma unroll
    for (int nb = 0; nb < 4; ++nb)
#pragma unroll
      for (int r = 0; r < 4; ++r) {
        float p = __expf(s[nb][r] - mnew);
        s[nb][r] = p;
        rs += p;
      }
    rs += __shfl_xor(rs, 16);
    rs += __shfl_xor(rs, 32);
    l_r = l_r * alpha + rs;

#pragma unroll
    for (int db = 0; db < 8; ++db)
#pragma unroll
      for (int r = 0; r < 4; ++r)
        acc[db][r] *= alpha;

    // P -> LDS: per lane 4x ds_write_b64, wave-private, swizzled
    u16* sPw = sP[wave];
#pragma unroll
    for (int nb = 0; nb < 4; ++nb) {
      u16x4 pk;
#pragma unroll
      for (int r = 0; r < 4; ++r) pk[r] = f2bf(s[nb][r]);
      *(u16x4*)&sPw[(l16 * 64 + nb * 16 + quad * 4) ^ ((l16 & 7) << 3)] = pk;
    }

    // PV swapped: O^T += V^T * P^T — A = Vt-frag (m = d), B = P-frag (n = q)
#pragma unroll
    for (int ch = 0; ch < 2; ++ch) {
      bf16x8 pf = *(const bf16x8*)&sPw[(l16 * 64 + ch * 32 + quad * 8) ^ ((l16 & 7) << 3)];
#pragma unroll
      for (int db = 0; db < 8; ++db) {
        bf16x8 vf = *(const bf16x8*)&sVt[((db * 16 + l16) * 64 + ch * 32 + quad * 8) ^ ((l16 & 7) << 3)];
        acc[db] = __builtin_amdgcn_mfma_f32_16x16x32_bf16(vf, pf, acc[db], 0, 0, 0);
      }
    }
  }

  // epilogue: normalize (per-lane), transpose via LDS (reuse sK), coalesced store
  float invl = 1.0f / l_r;
  __syncthreads();   // all waves done with sK/sVt reads
  u16* sOw = &sK[wave * 2048];   // per-wave [16 q][128 d] bf16, swizzled
#pragma unroll
  for (int db = 0; db < 8; ++db) {
    u16x4 pk;
#pragma unroll
    for (int r = 0; r < 4; ++r) pk[r] = f2bf(acc[db][r] * invl);
    *(u16x4*)&sOw[(l16 * 128 + db * 16 + quad * 4) ^ ((l16 & 7) << 3)] = pk;
  }
  // wave-private region: no barrier needed between write and read
#pragma unroll
  for (int p = 0; p < 4; ++p) {
    int row = p * 4 + quad;
    u16x8 o = *(const u16x8*)&sOw[(row * 128 + l16 * 8) ^ ((row & 7) << 3)];
    int q = qti * 64 + wave * 16 + row;
    *(u16x8*)(attn + ((size_t)(b * S_LEN + q)) * QSZ + (size_t)h * HD + l16 * 8) = o;
  }
}

extern "C" void kernel_launch(void* const* d_in, const int* in_sizes, int n_in,
                              void* d_out, int out_size, void* d_ws, size_t ws_size,
                              hipStream_t stream) {
  const float* hidden    = (const float*)d_in[0];
  const int*   positions = (const int*)d_in[1];
  const float* w_qkv     = (const float*)d_in[2];
  const float* b_qkv     = (const float*)d_in[3];
  const float* w_o       = (const float*)d_in[4];
  const float* b_o       = (const float*)d_in[5];
  float* out = (float*)d_out;

  char* ws = (char*)d_ws;
  const size_t MB = 1024 * 1024;
  u16*   hb    = (u16*)ws;                       // 0..32 MB   (gemm1 A)
  u16*   wqT   = (u16*)(ws + 32  * MB);          // 32..80 MB  (gemm1 B)
  u16*   woT   = (u16*)(ws + 80  * MB);          // 80..112 MB (gemm2 B)
  float* qkv   = (float*)(ws + 112 * MB);        // 112..208 MB
  u16*   attnb = (u16*)(ws + 208 * MB);          // 208..240 MB
  // overlays — alive only after gemm1 has consumed hb/wqT:
  u16*   Qb    = (u16*)ws;                       // 0..32 MB
  u16*   Kb    = (u16*)(ws + 32 * MB);           // 32..40 MB
  u16*   Vtb   = (u16*)(ws + 40 * MB);           // 40..48 MB

  cast_bf16_kernel<<<T_TOTAL * HIDDEN / 4 / 256, 256, 0, stream>>>(
      (const float4*)hidden, (ushort4*)hb, T_TOTAL * HIDDEN / 4);
  transpose_cast_kernel<<<dim3(QKV_N / 32, HIDDEN / 32), 256, 0, stream>>>(w_qkv, wqT, HIDDEN, QKV_N);
  transpose_cast_kernel<<<dim3(HIDDEN / 32, QSZ / 32), 256, 0, stream>>>(w_o, woT, QSZ, HIDDEN);
  gemm_pipe_kernel<<<dim3((T_TOTAL / 256) * (QKV_N / 256)), 512, 0, stream>>>(
      hb, wqT, b_qkv, qkv, T_TOTAL, QKV_N, HIDDEN, QKV_N / 256);
  qk_rope_cast_kernel<<<T_TOTAL * 2560 / 256, 256, 0, stream>>>(qkv, positions, Qb, Kb);
  v_transpose_cast_kernel<<<dim3(S_LEN / 32, HD / 32, 16), 256, 0, stream>>>(qkv, Vtb);
  flash_mfma_kernel<<<dim3(S_LEN / 64, NH, 2), 256, 0, stream>>>(Qb, Kb, Vtb, attnb);
  gemm_pipe_kernel<<<dim3((T_TOTAL / 256) * (HIDDEN / 256)), 512, 0, stream>>>(
      attnb, woT, b_o, out, T_TOTAL, HIDDEN, QSZ, HIDDEN / 256);
}

// Round 4
// 920.731 us; speedup vs baseline: 1.6695x; 1.0016x over previous
//
#include <hip/hip_runtime.h>
#include <cstdint>
#include <math.h>

#define T_TOTAL 4096
#define S_LEN   2048
#define NH      32
#define NKV     8
#define HD      128
#define HIDDEN  4096
#define QSZ     4096
#define KVSZ    1024
#define QKV_N   6144
#define SCALE_F 0.08838834764831843f   // 128^-0.5

typedef __bf16 bf16x8 __attribute__((ext_vector_type(8)));
typedef float  f32x4  __attribute__((ext_vector_type(4)));
typedef unsigned short u16;
typedef unsigned int   u32;
typedef u16 u16x8 __attribute__((ext_vector_type(8)));
typedef u16 u16x4 __attribute__((ext_vector_type(4)));

__device__ __forceinline__ u16 f2bf(float f) {
  u32 b = __float_as_uint(f);
  b += 0x7FFFu + ((b >> 16) & 1u);      // round-to-nearest-even
  return (u16)(b >> 16);
}

// async global->LDS, 16B per lane; LDS dst MUST be uniform base + lane*16
__device__ __forceinline__ void async_copy16(const u16* g, u16* l) {
  __builtin_amdgcn_global_load_lds(
      (const __attribute__((address_space(1))) void*)(g),
      (__attribute__((address_space(3))) void*)(l), 16, 0, 0);
}

// ---------------- fp32 -> bf16 cast (vectorized) ----------------
__global__ __launch_bounds__(256) void cast_bf16_kernel(const float4* __restrict__ in,
                                                        ushort4* __restrict__ out, int n4) {
  int i = blockIdx.x * 256 + threadIdx.x;
  if (i >= n4) return;
  float4 v = in[i];
  ushort4 o;
  o.x = f2bf(v.x); o.y = f2bf(v.y); o.z = f2bf(v.z); o.w = f2bf(v.w);
  out[i] = o;
}

// ---------------- fp32 [R][C] -> bf16 [C][R] transpose-cast ----------------
__global__ __launch_bounds__(256) void transpose_cast_kernel(const float* __restrict__ in,
                                                             u16* __restrict__ out, int R, int C) {
  __shared__ float tile[32][33];
  int bx = blockIdx.x * 32;
  int by = blockIdx.y * 32;
  int tx = threadIdx.x & 31, ty = threadIdx.x >> 5;
  for (int i = ty; i < 32; i += 8)
    tile[i][tx] = in[(size_t)(by + i) * C + bx + tx];
  __syncthreads();
  for (int i = ty; i < 32; i += 8)
    out[(size_t)(bx + i) * R + by + tx] = f2bf(tile[tx][i]);
}

// ---------------- pipelined bf16 MFMA GEMM: C = A * Bt^T + bias ----------------
// 256x256 tile, BK=32, 512 threads (8 waves as 2Mx4N), 2-slot LDS ring (64 KB ->
// 2 blocks/CU: round-3's 96KB ring capped at 1 block/CU, no inter-block overlap
// and a 1.5-round tail on gemm1), counted vmcnt (T4: never 0 in steady state),
// raw s_barrier, XOR-swizzled LDS via pre-swizzled global source (rule 21;
// round-3 measured SQ_LDS_BANK_CONFLICT == 0), setprio around MFMA cluster (T5),
// XCD-bijective block swizzle (T1).
__global__ __launch_bounds__(512) void gemm_pipe_kernel(const u16* __restrict__ A,
                                                        const u16* __restrict__ Bt,
                                                        const float* __restrict__ bias,
                                                        float* __restrict__ C,
                                                        int M, int N, int K, int nbn) {
  __shared__ u16 lds[2][2][8192];   // [slot][A|B][256 rows x 32 k], 64 KB
  const int tid  = threadIdx.x;
  const int lane = tid & 63, wave = tid >> 6;
  const int quad = lane >> 4, l16 = lane & 15;
  const int wm = (wave >> 2) * 128;   // wave M-offset (2 rows of waves)
  const int wn = (wave & 3) * 64;     // wave N-offset (4 cols of waves)

  // XCD-aware bijective swizzle (both call sites: gridDim.x % 8 == 0)
  const int cpx = gridDim.x >> 3;
  const int logical = (blockIdx.x & 7) * cpx + (blockIdx.x >> 3);
  const int bm = logical / nbn, bn = logical % nbn;

  // Staging: thread t owns row = e*128 + (t>>2), 16B chunk (t&3) of the slot.
  // LDS dest is linear (gload_lds requirement); the XOR swizzle is carried by
  // the global source chunk: g = (t&3) ^ ((row>>1)&3) = (t&3) ^ ((t>>3)&3).
  const int trow = tid >> 2;
  const int gch  = ((tid & 3) ^ ((tid >> 3) & 3)) * 8;
  const u16* gA = A  + (size_t)(bm * 256 + trow) * K + gch;
  const u16* gB = Bt + (size_t)(bn * 256 + trow) * K + gch;
  const size_t eoff = (size_t)128 * K;

  const int NT = K >> 5;
  // prologue: stage K-tiles 0,1 into slots 0,1 (issue order = vmcnt order)
#pragma unroll
  for (int pt = 0; pt < 2; ++pt) {
    int kt = pt * 32;
    async_copy16(gA + kt,        &lds[pt][0][tid * 8]);
    async_copy16(gA + eoff + kt, &lds[pt][0][4096 + tid * 8]);
    async_copy16(gB + kt,        &lds[pt][1][tid * 8]);
    async_copy16(gB + eoff + kt, &lds[pt][1][4096 + tid * 8]);
  }

  // frag-read swizzled chunk: quad ^ ((row>>1)&3); row low bits come from l16
  const int sw = (quad ^ ((l16 >> 1) & 3)) * 8;
  f32x4 acc[8][4] = {};
  for (int t = 0; t < NT; ++t) {
    if (t + 1 < NT) asm volatile("s_waitcnt vmcnt(4)" ::: "memory");  // tile t landed; t+1 in flight
    else            asm volatile("s_waitcnt vmcnt(0)" ::: "memory");
    __builtin_amdgcn_s_barrier();   // tile t visible to all waves

    const u16* sAt = lds[t & 1][0];
    const u16* sBt = lds[t & 1][1];
    bf16x8 af[8], bfr[4];
#pragma unroll
    for (int i = 0; i < 8; ++i)
      af[i] = *(const bf16x8*)&sAt[(wm + i * 16 + l16) * 32 + sw];
#pragma unroll
    for (int j = 0; j < 4; ++j)
      bfr[j] = *(const bf16x8*)&sBt[(wn + j * 16 + l16) * 32 + sw];
    asm volatile("s_waitcnt lgkmcnt(0)" ::: "memory");
    __builtin_amdgcn_s_barrier();   // all waves done reading slot (t&1)

    if (t + 2 < NT) {               // restage the freed slot; loads fly across barriers
      int kt = (t + 2) * 32;
      async_copy16(gA + kt,        &lds[t & 1][0][tid * 8]);
      async_copy16(gA + eoff + kt, &lds[t & 1][0][4096 + tid * 8]);
      async_copy16(gB + kt,        &lds[t & 1][1][tid * 8]);
      async_copy16(gB + eoff + kt, &lds[t & 1][1][4096 + tid * 8]);
    }

    __builtin_amdgcn_s_setprio(1);
#pragma unroll
    for (int i = 0; i < 8; ++i)
#pragma unroll
      for (int j = 0; j < 4; ++j)
        acc[i][j] = __builtin_amdgcn_mfma_f32_16x16x32_bf16(af[i], bfr[j], acc[i][j], 0, 0, 0);
    __builtin_amdgcn_s_setprio(0);
  }

  // epilogue: bias + fp32 store (C row = bm*256+wm+i*16+quad*4+r, col = bn*256+wn+j*16+l16)
#pragma unroll
  for (int i = 0; i < 8; ++i) {
    int row0 = bm * 256 + wm + i * 16 + quad * 4;
#pragma unroll
    for (int j = 0; j < 4; ++j) {
      int col = bn * 256 + wn + j * 16 + l16;
      float bi = bias[col];
#pragma unroll
      for (int r = 0; r < 4; ++r)
        C[(size_t)(row0 + r) * N + col] = acc[i][j][r] + bi;
    }
  }
}

// ---------------- RoPE + cast + layout for Q,K (bf16), scale folded into Q ----------------
__global__ __launch_bounds__(256) void qk_rope_cast_kernel(const float* __restrict__ qkv,
                                                           const int* __restrict__ pos,
                                                           u16* __restrict__ Qb,
                                                           u16* __restrict__ Kb) {
  int idx = blockIdx.x * 256 + threadIdx.x;   // T * 40 heads * 64 pairs
  int t = idx / 2560;
  int rem = idx - t * 2560;
  int head = rem >> 6, i = rem & 63;
  int b = t >> 11, s = t & 2047;
  float p = (float)pos[t];
  float inv = exp2f(-(float)i * 0.25952563f);   // (1e5)^(-2i/128)
  float f = p * inv;
  float sn, cs;
  sincosf(f, &sn, &cs);
  if (head < NH) {
    const float* src = qkv + (size_t)t * QKV_N + head * HD;
    float x1 = src[i], x2 = src[i + 64];
    u16* dst = Qb + (((size_t)(b * NH + head)) * S_LEN + s) * HD;
    dst[i]      = f2bf((x1 * cs - x2 * sn) * SCALE_F);
    dst[i + 64] = f2bf((x2 * cs + x1 * sn) * SCALE_F);
  } else {
    int kh = head - NH;
    const float* src = qkv + (size_t)t * QKV_N + QSZ + kh * HD;
    float x1 = src[i], x2 = src[i + 64];
    u16* dst = Kb + (((size_t)(b * NKV + kh)) * S_LEN + s) * HD;
    dst[i]      = f2bf(x1 * cs - x2 * sn);
    dst[i + 64] = f2bf(x2 * cs + x1 * sn);
  }
}

// ---------------- V transpose-cast: fp32 qkv -> bf16 Vtb [b][kvh][d=128][s=2048] ----------------
__global__ __launch_bounds__(256) void v_transpose_cast_kernel(const float* __restrict__ qkv,
                                                               u16* __restrict__ Vtb) {
  __shared__ float tile[32][33];
  int st = blockIdx.x * 32;
  int dt = blockIdx.y * 32;
  int bk = blockIdx.z;                      // b*8 + kvh
  int b = bk >> 3, kvh = bk & 7;
  int tx = threadIdx.x & 31, ty = threadIdx.x >> 5;
  const float* src = qkv + (size_t)(b * S_LEN) * QKV_N + QSZ + KVSZ + kvh * HD;
  for (int i = ty; i < 32; i += 8)
    tile[i][tx] = src[(size_t)(st + i) * QKV_N + dt + tx];
  __syncthreads();
  u16* dst = Vtb + (size_t)bk * HD * S_LEN;
  for (int i = ty; i < 32; i += 8)
    dst[(size_t)(dt + i) * S_LEN + st + tx] = f2bf(tile[tx][i]);
}

// ---------------- MFMA flash attention (causal, GQA 4:1) ----------------
// Swapped-operand structure: QK^T computed as mfma(K, Q) -> S^T (lane = q-row,
// k-index in registers) => in-lane softmax (2 cross-quad shuffles, per-lane m/l);
// PV computed as mfma(Vt, P) -> O^T (per-lane alpha rescale, no broadcasts).
// All LDS tiles XOR-swizzled ((row&7)<<3 on u16 index); 40 KB LDS.
// NOTE: no min-waves hint — launch_bounds(256,4) forced VGPR=64 and spilled
// everything to scratch (FETCH_SIZE 75MB -> 632MB, 2.1x slowdown). With
// natural allocation (~100-110 VGPR <= 128) the 40KB LDS still gives 4 blocks/CU.
__global__ __launch_bounds__(256) void flash_mfma_kernel(const u16* __restrict__ Qb,
                                                         const u16* __restrict__ Kb,
                                                         const u16* __restrict__ Vtb,
                                                         u16* __restrict__ attn) {
  const int qti = gridDim.x - 1 - blockIdx.x;   // long blocks launch first
  const int h = blockIdx.y, b = blockIdx.z;
  const int kvh = h >> 2;
  const int tid = threadIdx.x;
  const int lane = tid & 63, wave = tid >> 6;
  const int quad = lane >> 4, l16 = lane & 15;

  __shared__ u16 sK[64 * 128];     // [k-row][d]  swizzled, 16 KB
  __shared__ u16 sVt[128 * 64];    // [d][s]      swizzled, 16 KB
  __shared__ u16 sP[4][16 * 64];   // per-wave [q][k] swizzled, 8 KB

  // Q fragment (B-operand): lane l16 = q-row, elems = d-chunk quad*8+j
  bf16x8 qf[4];
  {
    const u16* qrow = Qb + (((size_t)(b * NH + h)) * S_LEN + (size_t)qti * 64 + wave * 16 + l16) * HD;
#pragma unroll
    for (int kc = 0; kc < 4; ++kc)
      qf[kc] = *(const bf16x8*)(qrow + kc * 32 + quad * 8);
  }

  f32x4 acc[8] = {};       // O^T: col l16 = q, rows quad*4+r = d within db*16
  float m_r = -INFINITY;   // per-lane running max for row q = l16
  float l_r = 0.f;

  const u16* Kbase = Kb  + ((size_t)(b * NKV + kvh)) * S_LEN * HD;
  const u16* Vbase = Vtb + ((size_t)(b * NKV + kvh)) * HD * S_LEN;

  // register prefetch buffers for next K/V tile
  u16x8 kv[4], vv[4];
#pragma unroll
  for (int i = 0; i < 4; ++i) {
    int c = i * 256 + tid;
    kv[i] = *(const u16x8*)(Kbase + (size_t)(c >> 4) * HD + (c & 15) * 8);
    vv[i] = *(const u16x8*)(Vbase + (size_t)(c >> 3) * S_LEN + (c & 7) * 8);
  }

  for (int kt = 0; kt <= qti; ++kt) {
    __syncthreads();   // previous compute done, LDS reusable
#pragma unroll
    for (int i = 0; i < 4; ++i) {
      int c = i * 256 + tid;
      int kr = c >> 4;
      *(u16x8*)&sK[(kr * 128 + (c & 15) * 8) ^ ((kr & 7) << 3)] = kv[i];
      int vr = c >> 3;
      *(u16x8*)&sVt[(vr * 64 + (c & 7) * 8) ^ ((vr & 7) << 3)] = vv[i];
    }
    __syncthreads();   // staging visible

    if (kt < qti) {    // prefetch next tile; vmcnt wait lands at next iter's LDS write
#pragma unroll
      for (int i = 0; i < 4; ++i) {
        int c = i * 256 + tid;
        kv[i] = *(const u16x8*)(Kbase + (size_t)((kt + 1) * 64 + (c >> 4)) * HD + (c & 15) * 8);
        vv[i] = *(const u16x8*)(Vbase + (size_t)(c >> 3) * S_LEN + (kt + 1) * 64 + (c & 7) * 8);
      }
    }

    // QK^T swapped: S^T[k][q] — A = K-frag (m = k-row), B = Q-frag (n = q-row)
    f32x4 s[4] = {};
#pragma unroll
    for (int kc = 0; kc < 4; ++kc) {
#pragma unroll
      for (int nb = 0; nb < 4; ++nb) {
        bf16x8 kf = *(const bf16x8*)&sK[((nb * 16 + l16) * 128 + kc * 32 + quad * 8) ^ ((l16 & 7) << 3)];
        s[nb] = __builtin_amdgcn_mfma_f32_16x16x32_bf16(kf, qf[kc], s[nb], 0, 0, 0);
      }
    }

    if (kt == qti) {   // causal mask on diagonal tile: k_local > q_local
      int qloc = wave * 16 + l16;
#pragma unroll
      for (int nb = 0; nb < 4; ++nb)
#pragma unroll
        for (int r = 0; r < 4; ++r)
          if (nb * 16 + quad * 4 + r > qloc) s[nb][r] = -1e30f;
    }

    // online softmax: lane owns row q = l16 (k-values split across quads)
    float mx = -1e30f;
#pragma unroll
    for (int nb = 0; nb < 4; ++nb)
#pragma unroll
      for (int r = 0; r < 4; ++r)
        mx = fmaxf(mx, s[nb][r]);
    mx = fmaxf(mx, __shfl_xor(mx, 16));
    mx = fmaxf(mx, __shfl_xor(mx, 32));
    float mnew = fmaxf(m_r, mx);
    float alpha = __expf(m_r - mnew);
    m_r = mnew;
    float rs = 0.f;
#pragma unroll
    for (int nb = 0; nb < 4; ++nb)
#pragma unroll
      for (int r = 0; r < 4; ++r) {
        float p = __expf(s[nb][r] - mnew);
        s[nb][r] = p;
        rs += p;
      }
    rs += __shfl_xor(rs, 16);
    rs += __shfl_xor(rs, 32);
    l_r = l_r * alpha + rs;

#pragma unroll
    for (int db = 0; db < 8; ++db)
#pragma unroll
      for (int r = 0; r < 4; ++r)
        acc[db][r] *= alpha;

    // P -> LDS: per lane 4x ds_write_b64, wave-private, swizzled
    u16* sPw = sP[wave];
#pragma unroll
    for (int nb = 0; nb < 4; ++nb) {
      u16x4 pk;
#pragma unroll
      for (int r = 0; r < 4; ++r) pk[r] = f2bf(s[nb][r]);
      *(u16x4*)&sPw[(l16 * 64 + nb * 16 + quad * 4) ^ ((l16 & 7) << 3)] = pk;
    }

    // PV swapped: O^T += V^T * P^T — A = Vt-frag (m = d), B = P-frag (n = q)
#pragma unroll
    for (int ch = 0; ch < 2; ++ch) {
      bf16x8 pf = *(const bf16x8*)&sPw[(l16 * 64 + ch * 32 + quad * 8) ^ ((l16 & 7) << 3)];
#pragma unroll
      for (int db = 0; db < 8; ++db) {
        bf16x8 vf = *(const bf16x8*)&sVt[((db * 16 + l16) * 64 + ch * 32 + quad * 8) ^ ((l16 & 7) << 3)];
        acc[db] = __builtin_amdgcn_mfma_f32_16x16x32_bf16(vf, pf, acc[db], 0, 0, 0);
      }
    }
  }

  // epilogue: normalize (per-lane), transpose via LDS (reuse sK), coalesced store
  float invl = 1.0f / l_r;
  __syncthreads();   // all waves done with sK/sVt reads
  u16* sOw = &sK[wave * 2048];   // per-wave [16 q][128 d] bf16, swizzled
#pragma unroll
  for (int db = 0; db < 8; ++db) {
    u16x4 pk;
#pragma unroll
    for (int r = 0; r < 4; ++r) pk[r] = f2bf(acc[db][r] * invl);
    *(u16x4*)&sOw[(l16 * 128 + db * 16 + quad * 4) ^ ((l16 & 7) << 3)] = pk;
  }
  // wave-private region: no barrier needed between write and read
#pragma unroll
  for (int p = 0; p < 4; ++p) {
    int row = p * 4 + quad;
    u16x8 o = *(const u16x8*)&sOw[(row * 128 + l16 * 8) ^ ((row & 7) << 3)];
    int q = qti * 64 + wave * 16 + row;
    *(u16x8*)(attn + ((size_t)(b * S_LEN + q)) * QSZ + (size_t)h * HD + l16 * 8) = o;
  }
}

extern "C" void kernel_launch(void* const* d_in, const int* in_sizes, int n_in,
                              void* d_out, int out_size, void* d_ws, size_t ws_size,
                              hipStream_t stream) {
  const float* hidden    = (const float*)d_in[0];
  const int*   positions = (const int*)d_in[1];
  const float* w_qkv     = (const float*)d_in[2];
  const float* b_qkv     = (const float*)d_in[3];
  const float* w_o       = (const float*)d_in[4];
  const float* b_o       = (const float*)d_in[5];
  float* out = (float*)d_out;

  char* ws = (char*)d_ws;
  const size_t MB = 1024 * 1024;
  u16*   hb    = (u16*)ws;                       // 0..32 MB   (gemm1 A)
  u16*   wqT   = (u16*)(ws + 32  * MB);          // 32..80 MB  (gemm1 B)
  u16*   woT   = (u16*)(ws + 80  * MB);          // 80..112 MB (gemm2 B)
  float* qkv   = (float*)(ws + 112 * MB);        // 112..208 MB
  u16*   attnb = (u16*)(ws + 208 * MB);          // 208..240 MB
  // overlays — alive only after gemm1 has consumed hb/wqT:
  u16*   Qb    = (u16*)ws;                       // 0..32 MB
  u16*   Kb    = (u16*)(ws + 32 * MB);           // 32..40 MB
  u16*   Vtb   = (u16*)(ws + 40 * MB);           // 40..48 MB

  cast_bf16_kernel<<<T_TOTAL * HIDDEN / 4 / 256, 256, 0, stream>>>(
      (const float4*)hidden, (ushort4*)hb, T_TOTAL * HIDDEN / 4);
  transpose_cast_kernel<<<dim3(QKV_N / 32, HIDDEN / 32), 256, 0, stream>>>(w_qkv, wqT, HIDDEN, QKV_N);
  transpose_cast_kernel<<<dim3(HIDDEN / 32, QSZ / 32), 256, 0, stream>>>(w_o, woT, QSZ, HIDDEN);
  gemm_pipe_kernel<<<dim3((T_TOTAL / 256) * (QKV_N / 256)), 512, 0, stream>>>(
      hb, wqT, b_qkv, qkv, T_TOTAL, QKV_N, HIDDEN, QKV_N / 256);
  qk_rope_cast_kernel<<<T_TOTAL * 2560 / 256, 256, 0, stream>>>(qkv, positions, Qb, Kb);
  v_transpose_cast_kernel<<<dim3(S_LEN / 32, HD / 32, 16), 256, 0, stream>>>(qkv, Vtb);
  flash_mfma_kernel<<<dim3(S_LEN / 64, NH, 2), 256, 0, stream>>>(Qb, Kb, Vtb, attnb);
  gemm_pipe_kernel<<<dim3((T_TOTAL / 256) * (HIDDEN / 256)), 512, 0, stream>>>(
      attnb, woT, b_o, out, T_TOTAL, HIDDEN, QSZ, HIDDEN / 256);
}

// Round 5
// 887.701 us; speedup vs baseline: 1.7316x; 1.0372x over previous
//
#include <hip/hip_runtime.h>
#include <cstdint>
#include <math.h>

#define T_TOTAL 4096
#define S_LEN   2048
#define NH      32
#define NKV     8
#define HD      128
#define HIDDEN  4096
#define QSZ     4096
#define KVSZ    1024
#define QKV_N   6144
#define SCALE_F 0.08838834764831843f   // 128^-0.5

typedef __bf16 bf16x8 __attribute__((ext_vector_type(8)));
typedef float  f32x4  __attribute__((ext_vector_type(4)));
typedef unsigned short u16;
typedef unsigned int   u32;
typedef u16 u16x8 __attribute__((ext_vector_type(8)));
typedef u16 u16x4 __attribute__((ext_vector_type(4)));

__device__ __forceinline__ u16 f2bf(float f) {
  u32 b = __float_as_uint(f);
  b += 0x7FFFu + ((b >> 16) & 1u);      // round-to-nearest-even
  return (u16)(b >> 16);
}

// async global->LDS, 16B per lane; LDS dst MUST be uniform base + lane*16
__device__ __forceinline__ void async_copy16(const u16* g, u16* l) {
  __builtin_amdgcn_global_load_lds(
      (const __attribute__((address_space(1))) void*)(g),
      (__attribute__((address_space(3))) void*)(l), 16, 0, 0);
}

// ---------------- fp32 -> bf16 cast (vectorized) ----------------
__global__ __launch_bounds__(256) void cast_bf16_kernel(const float4* __restrict__ in,
                                                        ushort4* __restrict__ out, int n4) {
  int i = blockIdx.x * 256 + threadIdx.x;
  if (i >= n4) return;
  float4 v = in[i];
  ushort4 o;
  o.x = f2bf(v.x); o.y = f2bf(v.y); o.z = f2bf(v.z); o.w = f2bf(v.w);
  out[i] = o;
}

// ---------------- fp32 [R][C] -> bf16 [C][R] transpose-cast ----------------
__global__ __launch_bounds__(256) void transpose_cast_kernel(const float* __restrict__ in,
                                                             u16* __restrict__ out, int R, int C) {
  __shared__ float tile[32][33];
  int bx = blockIdx.x * 32;
  int by = blockIdx.y * 32;
  int tx = threadIdx.x & 31, ty = threadIdx.x >> 5;
  for (int i = ty; i < 32; i += 8)
    tile[i][tx] = in[(size_t)(by + i) * C + bx + tx];
  __syncthreads();
  for (int i = ty; i < 32; i += 8)
    out[(size_t)(bx + i) * R + by + tx] = f2bf(tile[tx][i]);
}

// ---------------- pipelined bf16 MFMA GEMM: C = A * Bt^T + bias ----------------
// 256x256 tile, BK=32, 512 threads (8 waves as 2Mx4N), 2-slot LDS ring (64 KB),
// counted vmcnt (T4), raw s_barrier, XOR-swizzled LDS via pre-swizzled global
// source (rule 21; measured SQ_LDS_BANK_CONFLICT == 0), setprio (T5), XCD swizzle (T1).
__global__ __launch_bounds__(512) void gemm_pipe_kernel(const u16* __restrict__ A,
                                                        const u16* __restrict__ Bt,
                                                        const float* __restrict__ bias,
                                                        float* __restrict__ C,
                                                        int M, int N, int K, int nbn) {
  __shared__ u16 lds[2][2][8192];   // [slot][A|B][256 rows x 32 k], 64 KB
  const int tid  = threadIdx.x;
  const int lane = tid & 63, wave = tid >> 6;
  const int quad = lane >> 4, l16 = lane & 15;
  const int wm = (wave >> 2) * 128;   // wave M-offset (2 rows of waves)
  const int wn = (wave & 3) * 64;     // wave N-offset (4 cols of waves)

  // XCD-aware bijective swizzle (both call sites: gridDim.x % 8 == 0)
  const int cpx = gridDim.x >> 3;
  const int logical = (blockIdx.x & 7) * cpx + (blockIdx.x >> 3);
  const int bm = logical / nbn, bn = logical % nbn;

  // Staging: thread t owns row = e*128 + (t>>2), 16B chunk (t&3) of the slot.
  // LDS dest linear (gload_lds requirement); XOR swizzle carried by global source.
  const int trow = tid >> 2;
  const int gch  = ((tid & 3) ^ ((tid >> 3) & 3)) * 8;
  const u16* gA = A  + (size_t)(bm * 256 + trow) * K + gch;
  const u16* gB = Bt + (size_t)(bn * 256 + trow) * K + gch;
  const size_t eoff = (size_t)128 * K;

  const int NT = K >> 5;
#pragma unroll
  for (int pt = 0; pt < 2; ++pt) {
    int kt = pt * 32;
    async_copy16(gA + kt,        &lds[pt][0][tid * 8]);
    async_copy16(gA + eoff + kt, &lds[pt][0][4096 + tid * 8]);
    async_copy16(gB + kt,        &lds[pt][1][tid * 8]);
    async_copy16(gB + eoff + kt, &lds[pt][1][4096 + tid * 8]);
  }

  const int sw = (quad ^ ((l16 >> 1) & 3)) * 8;
  f32x4 acc[8][4] = {};
  for (int t = 0; t < NT; ++t) {
    if (t + 1 < NT) asm volatile("s_waitcnt vmcnt(4)" ::: "memory");
    else            asm volatile("s_waitcnt vmcnt(0)" ::: "memory");
    __builtin_amdgcn_s_barrier();   // tile t visible to all waves

    const u16* sAt = lds[t & 1][0];
    const u16* sBt = lds[t & 1][1];
    bf16x8 af[8], bfr[4];
#pragma unroll
    for (int i = 0; i < 8; ++i)
      af[i] = *(const bf16x8*)&sAt[(wm + i * 16 + l16) * 32 + sw];
#pragma unroll
    for (int j = 0; j < 4; ++j)
      bfr[j] = *(const bf16x8*)&sBt[(wn + j * 16 + l16) * 32 + sw];
    asm volatile("s_waitcnt lgkmcnt(0)" ::: "memory");
    __builtin_amdgcn_s_barrier();   // all waves done reading slot (t&1)

    if (t + 2 < NT) {
      int kt = (t + 2) * 32;
      async_copy16(gA + kt,        &lds[t & 1][0][tid * 8]);
      async_copy16(gA + eoff + kt, &lds[t & 1][0][4096 + tid * 8]);
      async_copy16(gB + kt,        &lds[t & 1][1][tid * 8]);
      async_copy16(gB + eoff + kt, &lds[t & 1][1][4096 + tid * 8]);
    }

    __builtin_amdgcn_s_setprio(1);
#pragma unroll
    for (int i = 0; i < 8; ++i)
#pragma unroll
      for (int j = 0; j < 4; ++j)
        acc[i][j] = __builtin_amdgcn_mfma_f32_16x16x32_bf16(af[i], bfr[j], acc[i][j], 0, 0, 0);
    __builtin_amdgcn_s_setprio(0);
  }

#pragma unroll
  for (int i = 0; i < 8; ++i) {
    int row0 = bm * 256 + wm + i * 16 + quad * 4;
#pragma unroll
    for (int j = 0; j < 4; ++j) {
      int col = bn * 256 + wn + j * 16 + l16;
      float bi = bias[col];
#pragma unroll
      for (int r = 0; r < 4; ++r)
        C[(size_t)(row0 + r) * N + col] = acc[i][j][r] + bi;
    }
  }
}

// ---------------- RoPE + cast + layout for Q,K (bf16), scale folded into Q ----------------
__global__ __launch_bounds__(256) void qk_rope_cast_kernel(const float* __restrict__ qkv,
                                                           const int* __restrict__ pos,
                                                           u16* __restrict__ Qb,
                                                           u16* __restrict__ Kb) {
  int idx = blockIdx.x * 256 + threadIdx.x;   // T * 40 heads * 64 pairs
  int t = idx / 2560;
  int rem = idx - t * 2560;
  int head = rem >> 6, i = rem & 63;
  int b = t >> 11, s = t & 2047;
  float p = (float)pos[t];
  float inv = exp2f(-(float)i * 0.25952563f);   // (1e5)^(-2i/128)
  float f = p * inv;
  float sn, cs;
  sincosf(f, &sn, &cs);
  if (head < NH) {
    const float* src = qkv + (size_t)t * QKV_N + head * HD;
    float x1 = src[i], x2 = src[i + 64];
    u16* dst = Qb + (((size_t)(b * NH + head)) * S_LEN + s) * HD;
    dst[i]      = f2bf((x1 * cs - x2 * sn) * SCALE_F);
    dst[i + 64] = f2bf((x2 * cs + x1 * sn) * SCALE_F);
  } else {
    int kh = head - NH;
    const float* src = qkv + (size_t)t * QKV_N + QSZ + kh * HD;
    float x1 = src[i], x2 = src[i + 64];
    u16* dst = Kb + (((size_t)(b * NKV + kh)) * S_LEN + s) * HD;
    dst[i]      = f2bf(x1 * cs - x2 * sn);
    dst[i + 64] = f2bf(x2 * cs + x1 * sn);
  }
}

// ---------------- V transpose-cast: fp32 qkv -> bf16 Vtb [b][kvh][d=128][s=2048] ----------------
__global__ __launch_bounds__(256) void v_transpose_cast_kernel(const float* __restrict__ qkv,
                                                               u16* __restrict__ Vtb) {
  __shared__ float tile[32][33];
  int st = blockIdx.x * 32;
  int dt = blockIdx.y * 32;
  int bk = blockIdx.z;                      // b*8 + kvh
  int b = bk >> 3, kvh = bk & 7;
  int tx = threadIdx.x & 31, ty = threadIdx.x >> 5;
  const float* src = qkv + (size_t)(b * S_LEN) * QKV_N + QSZ + KVSZ + kvh * HD;
  for (int i = ty; i < 32; i += 8)
    tile[i][tx] = src[(size_t)(st + i) * QKV_N + dt + tx];
  __syncthreads();
  u16* dst = Vtb + (size_t)bk * HD * S_LEN;
  for (int i = ty; i < 32; i += 8)
    dst[(size_t)(dt + i) * S_LEN + st + tx] = f2bf(tile[tx][i]);
}

// ---------------- MFMA flash attention (causal, GQA 4:1) ----------------
// 128 q-rows per block, 8 waves (512 thr): same per-wave inner loop as before,
// but K/V staging + barriers amortize over 2x the MFMA work, and 8 waves/block
// give >=2 waves/SIMD for MFMA/VALU overlap (round-4 showed ~1 wave/SIMD,
// latency-dominated: MfmaUtil 10.9%, occupancy 11%).
// Swapped-operand: QK^T as mfma(K,Q) -> S^T (lane = q-row, in-lane softmax);
// PV as mfma(Vt,P) -> O^T (per-lane alpha). XOR-swizzled LDS. Defer-max (T13).
// Causal: waves 0-3 skip the final fully-masked k-tile (wave-uniform branch).
__global__ __launch_bounds__(512) void flash_mfma_kernel(const u16* __restrict__ Qb,
                                                         const u16* __restrict__ Kb,
                                                         const u16* __restrict__ Vtb,
                                                         u16* __restrict__ attn) {
  const int qti = gridDim.x - 1 - blockIdx.x;   // long blocks launch first
  const int h = blockIdx.y, b = blockIdx.z;
  const int kvh = h >> 2;
  const int tid = threadIdx.x;
  const int lane = tid & 63, wave = tid >> 6;
  const int quad = lane >> 4, l16 = lane & 15;

  // 48 KB: sK 64x128 (16K) | sVt 128x64 (16K) | sP 8 waves x 16x64 (16K)
  __shared__ u16 smem[24576];
  u16* sK  = smem;
  u16* sVt = smem + 8192;
  u16* sPw = smem + 16384 + wave * 1024;

  // Q fragment (B-operand): lane l16 = q-row, elems = d-chunk quad*8+j
  bf16x8 qf[4];
  {
    const u16* qrow = Qb + (((size_t)(b * NH + h)) * S_LEN + (size_t)qti * 128 + wave * 16 + l16) * HD;
#pragma unroll
    for (int kc = 0; kc < 4; ++kc)
      qf[kc] = *(const bf16x8*)(qrow + kc * 32 + quad * 8);
  }

  f32x4 acc[8] = {};       // O^T: col l16 = q, rows quad*4+r = d within db*16
  float m_r = -INFINITY;   // per-lane running max for row q = l16
  float l_r = 0.f;

  const u16* Kbase = Kb  + ((size_t)(b * NKV + kvh)) * S_LEN * HD;
  const u16* Vbase = Vtb + ((size_t)(b * NKV + kvh)) * HD * S_LEN;

  // register prefetch buffers for next K/V tile (512 threads: 2 chunks each)
  u16x8 kv[2], vv[2];
#pragma unroll
  for (int i = 0; i < 2; ++i) {
    int c = i * 512 + tid;
    kv[i] = *(const u16x8*)(Kbase + (size_t)(c >> 4) * HD + (c & 15) * 8);
    vv[i] = *(const u16x8*)(Vbase + (size_t)(c >> 3) * S_LEN + (c & 7) * 8);
  }

  const int nkt = 2 * qti + 2;                 // 64-wide k-tiles for this block
  const int lastkt = 2 * qti + (wave >> 2);    // last useful tile for this wave

  for (int kt = 0; kt < nkt; ++kt) {
    __syncthreads();   // previous compute done, LDS reusable
#pragma unroll
    for (int i = 0; i < 2; ++i) {
      int c = i * 512 + tid;
      int kr = c >> 4;
      *(u16x8*)&sK[(kr * 128 + (c & 15) * 8) ^ ((kr & 7) << 3)] = kv[i];
      int vr = c >> 3;
      *(u16x8*)&sVt[(vr * 64 + (c & 7) * 8) ^ ((vr & 7) << 3)] = vv[i];
    }
    __syncthreads();   // staging visible

    if (kt + 1 < nkt) {   // prefetch next tile; vmcnt wait lands at next iter's LDS write
#pragma unroll
      for (int i = 0; i < 2; ++i) {
        int c = i * 512 + tid;
        kv[i] = *(const u16x8*)(Kbase + (size_t)((kt + 1) * 64 + (c >> 4)) * HD + (c & 15) * 8);
        vv[i] = *(const u16x8*)(Vbase + (size_t)(c >> 3) * S_LEN + (kt + 1) * 64 + (c & 7) * 8);
      }
    }

    if (kt > lastkt) continue;   // fully-masked tile for this wave (wave-uniform)

    // QK^T swapped: S^T[k][q] — A = K-frag (m = k-row), B = Q-frag (n = q-row)
    f32x4 s[4] = {};
#pragma unroll
    for (int kc = 0; kc < 4; ++kc) {
#pragma unroll
      for (int nb = 0; nb < 4; ++nb) {
        bf16x8 kf = *(const bf16x8*)&sK[((nb * 16 + l16) * 128 + kc * 32 + quad * 8) ^ ((l16 & 7) << 3)];
        s[nb] = __builtin_amdgcn_mfma_f32_16x16x32_bf16(kf, qf[kc], s[nb], 0, 0, 0);
      }
    }

    if (kt == lastkt) {   // causal mask on this wave's diagonal tile
      int qg = qti * 128 + wave * 16 + l16;
      int k0 = kt * 64;
#pragma unroll
      for (int nb = 0; nb < 4; ++nb)
#pragma unroll
        for (int r = 0; r < 4; ++r)
          if (k0 + nb * 16 + quad * 4 + r > qg) s[nb][r] = -1e30f;
    }

    // online softmax with defer-max (T13, THR=8): lane owns row q = l16
    float mx = -1e30f;
#pragma unroll
    for (int nb = 0; nb < 4; ++nb)
#pragma unroll
      for (int r = 0; r < 4; ++r)
        mx = fmaxf(mx, s[nb][r]);
    float alpha = 1.f;
    if (!__all(mx - m_r <= 8.f)) {
      mx = fmaxf(mx, __shfl_xor(mx, 16));
      mx = fmaxf(mx, __shfl_xor(mx, 32));
      float mnew = fmaxf(m_r, mx);
      alpha = __expf(m_r - mnew);
      m_r = mnew;
#pragma unroll
      for (int db = 0; db < 8; ++db)
#pragma unroll
        for (int r = 0; r < 4; ++r)
          acc[db][r] *= alpha;
    }
    float rs = 0.f;
#pragma unroll
    for (int nb = 0; nb < 4; ++nb)
#pragma unroll
      for (int r = 0; r < 4; ++r) {
        float p = __expf(s[nb][r] - m_r);
        s[nb][r] = p;
        rs += p;
      }
    rs += __shfl_xor(rs, 16);
    rs += __shfl_xor(rs, 32);
    l_r = l_r * alpha + rs;

    // P -> LDS: per lane 4x ds_write_b64, wave-private, swizzled
#pragma unroll
    for (int nb = 0; nb < 4; ++nb) {
      u16x4 pk;
#pragma unroll
      for (int r = 0; r < 4; ++r) pk[r] = f2bf(s[nb][r]);
      *(u16x4*)&sPw[(l16 * 64 + nb * 16 + quad * 4) ^ ((l16 & 7) << 3)] = pk;
    }

    // PV swapped: O^T += V^T * P^T — A = Vt-frag (m = d), B = P-frag (n = q)
#pragma unroll
    for (int ch = 0; ch < 2; ++ch) {
      bf16x8 pf = *(const bf16x8*)&sPw[(l16 * 64 + ch * 32 + quad * 8) ^ ((l16 & 7) << 3)];
#pragma unroll
      for (int db = 0; db < 8; ++db) {
        bf16x8 vf = *(const bf16x8*)&sVt[((db * 16 + l16) * 64 + ch * 32 + quad * 8) ^ ((l16 & 7) << 3)];
        acc[db] = __builtin_amdgcn_mfma_f32_16x16x32_bf16(vf, pf, acc[db], 0, 0, 0);
      }
    }
  }

  // epilogue: normalize (per-lane), transpose via LDS (reuse sK/sVt), coalesced store
  float invl = 1.0f / l_r;
  __syncthreads();   // all waves done with sK/sVt reads
  u16* sOw = &smem[wave * 2048];   // per-wave [16 q][128 d] bf16, swizzled
#pragma unroll
  for (int db = 0; db < 8; ++db) {
    u16x4 pk;
#pragma unroll
    for (int r = 0; r < 4; ++r) pk[r] = f2bf(acc[db][r] * invl);
    *(u16x4*)&sOw[(l16 * 128 + db * 16 + quad * 4) ^ ((l16 & 7) << 3)] = pk;
  }
  // wave-private region: no barrier needed between write and read
#pragma unroll
  for (int p = 0; p < 4; ++p) {
    int row = p * 4 + quad;
    u16x8 o = *(const u16x8*)&sOw[(row * 128 + l16 * 8) ^ ((row & 7) << 3)];
    int q = qti * 128 + wave * 16 + row;
    *(u16x8*)(attn + ((size_t)(b * S_LEN + q)) * QSZ + (size_t)h * HD + l16 * 8) = o;
  }
}

extern "C" void kernel_launch(void* const* d_in, const int* in_sizes, int n_in,
                              void* d_out, int out_size, void* d_ws, size_t ws_size,
                              hipStream_t stream) {
  const float* hidden    = (const float*)d_in[0];
  const int*   positions = (const int*)d_in[1];
  const float* w_qkv     = (const float*)d_in[2];
  const float* b_qkv     = (const float*)d_in[3];
  const float* w_o       = (const float*)d_in[4];
  const float* b_o       = (const float*)d_in[5];
  float* out = (float*)d_out;

  char* ws = (char*)d_ws;
  const size_t MB = 1024 * 1024;
  u16*   hb    = (u16*)ws;                       // 0..32 MB   (gemm1 A)
  u16*   wqT   = (u16*)(ws + 32  * MB);          // 32..80 MB  (gemm1 B)
  u16*   woT   = (u16*)(ws + 80  * MB);          // 80..112 MB (gemm2 B)
  float* qkv   = (float*)(ws + 112 * MB);        // 112..208 MB
  u16*   attnb = (u16*)(ws + 208 * MB);          // 208..240 MB
  // overlays — alive only after gemm1 has consumed hb/wqT:
  u16*   Qb    = (u16*)ws;                       // 0..32 MB
  u16*   Kb    = (u16*)(ws + 32 * MB);           // 32..40 MB
  u16*   Vtb   = (u16*)(ws + 40 * MB);           // 40..48 MB

  cast_bf16_kernel<<<T_TOTAL * HIDDEN / 4 / 256, 256, 0, stream>>>(
      (const float4*)hidden, (ushort4*)hb, T_TOTAL * HIDDEN / 4);
  transpose_cast_kernel<<<dim3(QKV_N / 32, HIDDEN / 32), 256, 0, stream>>>(w_qkv, wqT, HIDDEN, QKV_N);
  transpose_cast_kernel<<<dim3(HIDDEN / 32, QSZ / 32), 256, 0, stream>>>(w_o, woT, QSZ, HIDDEN);
  gemm_pipe_kernel<<<dim3((T_TOTAL / 256) * (QKV_N / 256)), 512, 0, stream>>>(
      hb, wqT, b_qkv, qkv, T_TOTAL, QKV_N, HIDDEN, QKV_N / 256);
  qk_rope_cast_kernel<<<T_TOTAL * 2560 / 256, 256, 0, stream>>>(qkv, positions, Qb, Kb);
  v_transpose_cast_kernel<<<dim3(S_LEN / 32, HD / 32, 16), 256, 0, stream>>>(qkv, Vtb);
  flash_mfma_kernel<<<dim3(S_LEN / 128, NH, 2), 512, 0, stream>>>(Qb, Kb, Vtb, attnb);
  gemm_pipe_kernel<<<dim3((T_TOTAL / 256) * (HIDDEN / 256)), 512, 0, stream>>>(
      attnb, woT, b_o, out, T_TOTAL, HIDDEN, QSZ, HIDDEN / 256);
}

// Round 6
// 887.570 us; speedup vs baseline: 1.7318x; 1.0001x over previous
//
#include <hip/hip_runtime.h>
#include <cstdint>
#include <math.h>

#define T_TOTAL 4096
#define S_LEN   2048
#define NH      32
#define NKV     8
#define HD      128
#define HIDDEN  4096
#define QSZ     4096
#define KVSZ    1024
#define QKV_N   6144
#define SCALE_F 0.08838834764831843f   // 128^-0.5

typedef __bf16 bf16x8 __attribute__((ext_vector_type(8)));
typedef float  f32x4  __attribute__((ext_vector_type(4)));
typedef unsigned short u16;
typedef unsigned int   u32;
typedef u16 u16x8 __attribute__((ext_vector_type(8)));
typedef u16 u16x4 __attribute__((ext_vector_type(4)));

__device__ __forceinline__ u16 f2bf(float f) {
  u32 b = __float_as_uint(f);
  b += 0x7FFFu + ((b >> 16) & 1u);      // round-to-nearest-even
  return (u16)(b >> 16);
}

// async global->LDS, 16B per lane; LDS dst MUST be uniform base + lane*16
__device__ __forceinline__ void async_copy16(const u16* g, u16* l) {
  __builtin_amdgcn_global_load_lds(
      (const __attribute__((address_space(1))) void*)(g),
      (__attribute__((address_space(3))) void*)(l), 16, 0, 0);
}

// ---------------- fp32 -> bf16 cast (vectorized) ----------------
__global__ __launch_bounds__(256) void cast_bf16_kernel(const float4* __restrict__ in,
                                                        ushort4* __restrict__ out, int n4) {
  int i = blockIdx.x * 256 + threadIdx.x;
  if (i >= n4) return;
  float4 v = in[i];
  ushort4 o;
  o.x = f2bf(v.x); o.y = f2bf(v.y); o.z = f2bf(v.z); o.w = f2bf(v.w);
  out[i] = o;
}

// ---------------- fp32 [R][C] -> bf16 [C][R] transpose-cast ----------------
__global__ __launch_bounds__(256) void transpose_cast_kernel(const float* __restrict__ in,
                                                             u16* __restrict__ out, int R, int C) {
  __shared__ float tile[32][33];
  int bx = blockIdx.x * 32;
  int by = blockIdx.y * 32;
  int tx = threadIdx.x & 31, ty = threadIdx.x >> 5;
  for (int i = ty; i < 32; i += 8)
    tile[i][tx] = in[(size_t)(by + i) * C + bx + tx];
  __syncthreads();
  for (int i = ty; i < 32; i += 8)
    out[(size_t)(bx + i) * R + by + tx] = f2bf(tile[tx][i]);
}

// ---------------- fine-phase pipelined bf16 MFMA GEMM: C = A * Bt^T + bias ----------------
// BM=128 BN=256 BK=32, 512 thr (8 waves, each 64x64 out). Per phase:
// {vmcnt(3); s_barrier; stage tile t+2 (3 gload_lds); 8 ds_read_b128; lgkmcnt(0);
//  setprio(1); 16 MFMA; setprio(0)} — ONE barrier per phase, vmcnt never 0 until
// the final tile (T3+T4). 3-slot ring, 72 KB -> 2 blocks/CU. Round-5's 2-barrier
// lockstep structure measured MfmaUtil 33% / VALUBusy 13%: stage+drain+barrier
// dominated (m233 regime). XOR swizzle identical to the measured-0-conflict layout.
// Single-barrier safety: a wave stages into slot (t+2)%3 only after the iter-t
// barrier, which all waves reach only after lgkmcnt(0)-complete reads of slot t;
// slot (t+2)%3 held tile t-1, fully consumed before that barrier.
__global__ __launch_bounds__(512) void gemm_pipe_kernel(const u16* __restrict__ A,
                                                        const u16* __restrict__ Bt,
                                                        const float* __restrict__ bias,
                                                        float* __restrict__ C,
                                                        int M, int N, int K, int nbn) {
  __shared__ u16 lds[3][12288];   // slot: A[128x32] (4096 u16) | B[256x32] (8192 u16) = 24 KB
  const int tid  = threadIdx.x;
  const int lane = tid & 63, wave = tid >> 6;
  const int quad = lane >> 4, l16 = lane & 15;
  const int wm = (wave >> 2) * 64;    // wave M-offset (2 rows of waves)
  const int wn = (wave & 3) * 64;     // wave N-offset (4 cols of waves)

  // XCD-aware bijective swizzle (both call sites: gridDim.x % 8 == 0)
  const int cpx = gridDim.x >> 3;
  const int logical = (blockIdx.x & 7) * cpx + (blockIdx.x >> 3);
  const int bm = logical / nbn, bn = logical % nbn;

  // Staging: rows of 32 bf16 = 4 chunks of 16B. Thread t owns row t>>2, chunk t&3.
  // LDS dest linear (gload_lds requirement); XOR swizzle carried by global source:
  // g_chunk = (t&3) ^ ((row>>1)&3) = (t&3) ^ ((t>>3)&3)  (same for B rows +128).
  const int gch = ((tid & 3) ^ ((tid >> 3) & 3)) * 8;
  const u16* gA  = A  + (size_t)(bm * 128 + (tid >> 2)) * K + gch;
  const u16* gB0 = Bt + (size_t)(bn * 256 + (tid >> 2)) * K + gch;
  const u16* gB1 = gB0 + (size_t)128 * K;

  const int NT = K >> 5;
  // prologue: stage tiles 0,1 into slots 0,1 (3 loads each, issue order = vmcnt order)
#pragma unroll
  for (int pt = 0; pt < 2; ++pt) {
    int kt = pt * 32;
    async_copy16(gA  + kt, &lds[pt][tid * 8]);
    async_copy16(gB0 + kt, &lds[pt][4096 + tid * 8]);
    async_copy16(gB1 + kt, &lds[pt][8192 + tid * 8]);
  }

  // frag-read swizzled chunk: quad ^ ((row>>1)&3); row low bits come from l16.
  const int sw = (quad ^ ((l16 >> 1) & 3)) * 8;
  f32x4 acc[4][4] = {};
  int sl = 0;                     // slot of tile t
  for (int t = 0; t < NT; ++t) {
    if (t + 1 < NT) asm volatile("s_waitcnt vmcnt(3)" ::: "memory");  // tile t landed; t+1 in flight
    else            asm volatile("s_waitcnt vmcnt(0)" ::: "memory");
    __builtin_amdgcn_s_barrier();  // tile t visible; slot s2's old reads all done

    int s2 = (sl == 0) ? 2 : sl - 1;   // (sl+2)%3 — slot that held tile t-1
    if (t + 2 < NT) {                  // stage tile t+2; loads fly across phases
      int kt = (t + 2) * 32;
      async_copy16(gA  + kt, &lds[s2][tid * 8]);
      async_copy16(gB0 + kt, &lds[s2][4096 + tid * 8]);
      async_copy16(gB1 + kt, &lds[s2][8192 + tid * 8]);
    }

    const u16* sAt = lds[sl];
    const u16* sBt = &lds[sl][4096];
    bf16x8 af[4], bfr[4];
#pragma unroll
    for (int i = 0; i < 4; ++i)
      af[i] = *(const bf16x8*)&sAt[(wm + i * 16 + l16) * 32 + sw];
#pragma unroll
    for (int j = 0; j < 4; ++j)
      bfr[j] = *(const bf16x8*)&sBt[(wn + j * 16 + l16) * 32 + sw];
    asm volatile("s_waitcnt lgkmcnt(0)" ::: "memory");

    __builtin_amdgcn_s_setprio(1);
#pragma unroll
    for (int i = 0; i < 4; ++i)
#pragma unroll
      for (int j = 0; j < 4; ++j)
        acc[i][j] = __builtin_amdgcn_mfma_f32_16x16x32_bf16(af[i], bfr[j], acc[i][j], 0, 0, 0);
    __builtin_amdgcn_s_setprio(0);

    sl = (sl == 2) ? 0 : sl + 1;
  }

  // epilogue: bias + fp32 store (row = bm*128 + wm + i*16 + quad*4 + r, col = bn*256 + wn + j*16 + l16)
#pragma unroll
  for (int i = 0; i < 4; ++i) {
    int row0 = bm * 128 + wm + i * 16 + quad * 4;
#pragma unroll
    for (int j = 0; j < 4; ++j) {
      int col = bn * 256 + wn + j * 16 + l16;
      float bi = bias[col];
#pragma unroll
      for (int r = 0; r < 4; ++r)
        C[(size_t)(row0 + r) * N + col] = acc[i][j][r] + bi;
    }
  }
}

// ---------------- RoPE + cast + layout for Q,K (bf16), scale folded into Q ----------------
__global__ __launch_bounds__(256) void qk_rope_cast_kernel(const float* __restrict__ qkv,
                                                           const int* __restrict__ pos,
                                                           u16* __restrict__ Qb,
                                                           u16* __restrict__ Kb) {
  int idx = blockIdx.x * 256 + threadIdx.x;   // T * 40 heads * 64 pairs
  int t = idx / 2560;
  int rem = idx - t * 2560;
  int head = rem >> 6, i = rem & 63;
  int b = t >> 11, s = t & 2047;
  float p = (float)pos[t];
  float inv = exp2f(-(float)i * 0.25952563f);   // (1e5)^(-2i/128)
  float f = p * inv;
  float sn, cs;
  sincosf(f, &sn, &cs);
  if (head < NH) {
    const float* src = qkv + (size_t)t * QKV_N + head * HD;
    float x1 = src[i], x2 = src[i + 64];
    u16* dst = Qb + (((size_t)(b * NH + head)) * S_LEN + s) * HD;
    dst[i]      = f2bf((x1 * cs - x2 * sn) * SCALE_F);
    dst[i + 64] = f2bf((x2 * cs + x1 * sn) * SCALE_F);
  } else {
    int kh = head - NH;
    const float* src = qkv + (size_t)t * QKV_N + QSZ + kh * HD;
    float x1 = src[i], x2 = src[i + 64];
    u16* dst = Kb + (((size_t)(b * NKV + kh)) * S_LEN + s) * HD;
    dst[i]      = f2bf(x1 * cs - x2 * sn);
    dst[i + 64] = f2bf(x2 * cs + x1 * sn);
  }
}

// ---------------- V transpose-cast: fp32 qkv -> bf16 Vtb [b][kvh][d=128][s=2048] ----------------
__global__ __launch_bounds__(256) void v_transpose_cast_kernel(const float* __restrict__ qkv,
                                                               u16* __restrict__ Vtb) {
  __shared__ float tile[32][33];
  int st = blockIdx.x * 32;
  int dt = blockIdx.y * 32;
  int bk = blockIdx.z;                      // b*8 + kvh
  int b = bk >> 3, kvh = bk & 7;
  int tx = threadIdx.x & 31, ty = threadIdx.x >> 5;
  const float* src = qkv + (size_t)(b * S_LEN) * QKV_N + QSZ + KVSZ + kvh * HD;
  for (int i = ty; i < 32; i += 8)
    tile[i][tx] = src[(size_t)(st + i) * QKV_N + dt + tx];
  __syncthreads();
  u16* dst = Vtb + (size_t)bk * HD * S_LEN;
  for (int i = ty; i < 32; i += 8)
    dst[(size_t)(dt + i) * S_LEN + st + tx] = f2bf(tile[tx][i]);
}

// ---------------- MFMA flash attention (causal, GQA 4:1) ----------------
// 128 q-rows per block, 8 waves (512 thr). Swapped-operand: QK^T as mfma(K,Q) ->
// S^T (lane = q-row, in-lane softmax); PV as mfma(Vt,P) -> O^T (per-lane alpha).
// XOR-swizzled LDS. Defer-max (T13). Causal wave-uniform skip of masked tiles.
__global__ __launch_bounds__(512) void flash_mfma_kernel(const u16* __restrict__ Qb,
                                                         const u16* __restrict__ Kb,
                                                         const u16* __restrict__ Vtb,
                                                         u16* __restrict__ attn) {
  const int qti = gridDim.x - 1 - blockIdx.x;   // long blocks launch first
  const int h = blockIdx.y, b = blockIdx.z;
  const int kvh = h >> 2;
  const int tid = threadIdx.x;
  const int lane = tid & 63, wave = tid >> 6;
  const int quad = lane >> 4, l16 = lane & 15;

  // 48 KB: sK 64x128 (16K) | sVt 128x64 (16K) | sP 8 waves x 16x64 (16K)
  __shared__ u16 smem[24576];
  u16* sK  = smem;
  u16* sVt = smem + 8192;
  u16* sPw = smem + 16384 + wave * 1024;

  // Q fragment (B-operand): lane l16 = q-row, elems = d-chunk quad*8+j
  bf16x8 qf[4];
  {
    const u16* qrow = Qb + (((size_t)(b * NH + h)) * S_LEN + (size_t)qti * 128 + wave * 16 + l16) * HD;
#pragma unroll
    for (int kc = 0; kc < 4; ++kc)
      qf[kc] = *(const bf16x8*)(qrow + kc * 32 + quad * 8);
  }

  f32x4 acc[8] = {};       // O^T: col l16 = q, rows quad*4+r = d within db*16
  float m_r = -INFINITY;   // per-lane running max for row q = l16
  float l_r = 0.f;

  const u16* Kbase = Kb  + ((size_t)(b * NKV + kvh)) * S_LEN * HD;
  const u16* Vbase = Vtb + ((size_t)(b * NKV + kvh)) * HD * S_LEN;

  // register prefetch buffers for next K/V tile (512 threads: 2 chunks each)
  u16x8 kv[2], vv[2];
#pragma unroll
  for (int i = 0; i < 2; ++i) {
    int c = i * 512 + tid;
    kv[i] = *(const u16x8*)(Kbase + (size_t)(c >> 4) * HD + (c & 15) * 8);
    vv[i] = *(const u16x8*)(Vbase + (size_t)(c >> 3) * S_LEN + (c & 7) * 8);
  }

  const int nkt = 2 * qti + 2;                 // 64-wide k-tiles for this block
  const int lastkt = 2 * qti + (wave >> 2);    // last useful tile for this wave

  for (int kt = 0; kt < nkt; ++kt) {
    __syncthreads();   // previous compute done, LDS reusable
#pragma unroll
    for (int i = 0; i < 2; ++i) {
      int c = i * 512 + tid;
      int kr = c >> 4;
      *(u16x8*)&sK[(kr * 128 + (c & 15) * 8) ^ ((kr & 7) << 3)] = kv[i];
      int vr = c >> 3;
      *(u16x8*)&sVt[(vr * 64 + (c & 7) * 8) ^ ((vr & 7) << 3)] = vv[i];
    }
    __syncthreads();   // staging visible

    if (kt + 1 < nkt) {   // prefetch next tile; vmcnt wait lands at next iter's LDS write
#pragma unroll
      for (int i = 0; i < 2; ++i) {
        int c = i * 512 + tid;
        kv[i] = *(const u16x8*)(Kbase + (size_t)((kt + 1) * 64 + (c >> 4)) * HD + (c & 15) * 8);
        vv[i] = *(const u16x8*)(Vbase + (size_t)(c >> 3) * S_LEN + (kt + 1) * 64 + (c & 7) * 8);
      }
    }

    if (kt > lastkt) continue;   // fully-masked tile for this wave (wave-uniform)

    // QK^T swapped: S^T[k][q] — A = K-frag (m = k-row), B = Q-frag (n = q-row)
    f32x4 s[4] = {};
#pragma unroll
    for (int kc = 0; kc < 4; ++kc) {
#pragma unroll
      for (int nb = 0; nb < 4; ++nb) {
        bf16x8 kf = *(const bf16x8*)&sK[((nb * 16 + l16) * 128 + kc * 32 + quad * 8) ^ ((l16 & 7) << 3)];
        s[nb] = __builtin_amdgcn_mfma_f32_16x16x32_bf16(kf, qf[kc], s[nb], 0, 0, 0);
      }
    }

    if (kt == lastkt) {   // causal mask on this wave's diagonal tile
      int qg = qti * 128 + wave * 16 + l16;
      int k0 = kt * 64;
#pragma unroll
      for (int nb = 0; nb < 4; ++nb)
#pragma unroll
        for (int r = 0; r < 4; ++r)
          if (k0 + nb * 16 + quad * 4 + r > qg) s[nb][r] = -1e30f;
    }

    // online softmax with defer-max (T13, THR=8): lane owns row q = l16
    float mx = -1e30f;
#pragma unroll
    for (int nb = 0; nb < 4; ++nb)
#pragma unroll
      for (int r = 0; r < 4; ++r)
        mx = fmaxf(mx, s[nb][r]);
    float alpha = 1.f;
    if (!__all(mx - m_r <= 8.f)) {
      mx = fmaxf(mx, __shfl_xor(mx, 16));
      mx = fmaxf(mx, __shfl_xor(mx, 32));
      float mnew = fmaxf(m_r, mx);
      alpha = __expf(m_r - mnew);
      m_r = mnew;
#pragma unroll
      for (int db = 0; db < 8; ++db)
#pragma unroll
        for (int r = 0; r < 4; ++r)
          acc[db][r] *= alpha;
    }
    float rs = 0.f;
#pragma unroll
    for (int nb = 0; nb < 4; ++nb)
#pragma unroll
      for (int r = 0; r < 4; ++r) {
        float p = __expf(s[nb][r] - m_r);
        s[nb][r] = p;
        rs += p;
      }
    rs += __shfl_xor(rs, 16);
    rs += __shfl_xor(rs, 32);
    l_r = l_r * alpha + rs;

    // P -> LDS: per lane 4x ds_write_b64, wave-private, swizzled
#pragma unroll
    for (int nb = 0; nb < 4; ++nb) {
      u16x4 pk;
#pragma unroll
      for (int r = 0; r < 4; ++r) pk[r] = f2bf(s[nb][r]);
      *(u16x4*)&sPw[(l16 * 64 + nb * 16 + quad * 4) ^ ((l16 & 7) << 3)] = pk;
    }

    // PV swapped: O^T += V^T * P^T — A = Vt-frag (m = d), B = P-frag (n = q)
#pragma unroll
    for (int ch = 0; ch < 2; ++ch) {
      bf16x8 pf = *(const bf16x8*)&sPw[(l16 * 64 + ch * 32 + quad * 8) ^ ((l16 & 7) << 3)];
#pragma unroll
      for (int db = 0; db < 8; ++db) {
        bf16x8 vf = *(const bf16x8*)&sVt[((db * 16 + l16) * 64 + ch * 32 + quad * 8) ^ ((l16 & 7) << 3)];
        acc[db] = __builtin_amdgcn_mfma_f32_16x16x32_bf16(vf, pf, acc[db], 0, 0, 0);
      }
    }
  }

  // epilogue: normalize (per-lane), transpose via LDS (reuse smem), coalesced store
  float invl = 1.0f / l_r;
  __syncthreads();   // all waves done with sK/sVt reads
  u16* sOw = &smem[wave * 2048];   // per-wave [16 q][128 d] bf16, swizzled
#pragma unroll
  for (int db = 0; db < 8; ++db) {
    u16x4 pk;
#pragma unroll
    for (int r = 0; r < 4; ++r) pk[r] = f2bf(acc[db][r] * invl);
    *(u16x4*)&sOw[(l16 * 128 + db * 16 + quad * 4) ^ ((l16 & 7) << 3)] = pk;
  }
  // wave-private region: no barrier needed between write and read
#pragma unroll
  for (int p = 0; p < 4; ++p) {
    int row = p * 4 + quad;
    u16x8 o = *(const u16x8*)&sOw[(row * 128 + l16 * 8) ^ ((row & 7) << 3)];
    int q = qti * 128 + wave * 16 + row;
    *(u16x8*)(attn + ((size_t)(b * S_LEN + q)) * QSZ + (size_t)h * HD + l16 * 8) = o;
  }
}

extern "C" void kernel_launch(void* const* d_in, const int* in_sizes, int n_in,
                              void* d_out, int out_size, void* d_ws, size_t ws_size,
                              hipStream_t stream) {
  const float* hidden    = (const float*)d_in[0];
  const int*   positions = (const int*)d_in[1];
  const float* w_qkv     = (const float*)d_in[2];
  const float* b_qkv     = (const float*)d_in[3];
  const float* w_o       = (const float*)d_in[4];
  const float* b_o       = (const float*)d_in[5];
  float* out = (float*)d_out;

  char* ws = (char*)d_ws;
  const size_t MB = 1024 * 1024;
  u16*   hb    = (u16*)ws;                       // 0..32 MB   (gemm1 A)
  u16*   wqT   = (u16*)(ws + 32  * MB);          // 32..80 MB  (gemm1 B)
  u16*   woT   = (u16*)(ws + 80  * MB);          // 80..112 MB (gemm2 B)
  float* qkv   = (float*)(ws + 112 * MB);        // 112..208 MB
  u16*   attnb = (u16*)(ws + 208 * MB);          // 208..240 MB
  // overlays — alive only after gemm1 has consumed hb/wqT:
  u16*   Qb    = (u16*)ws;                       // 0..32 MB
  u16*   Kb    = (u16*)(ws + 32 * MB);           // 32..40 MB
  u16*   Vtb   = (u16*)(ws + 40 * MB);           // 40..48 MB

  cast_bf16_kernel<<<T_TOTAL * HIDDEN / 4 / 256, 256, 0, stream>>>(
      (const float4*)hidden, (ushort4*)hb, T_TOTAL * HIDDEN / 4);
  transpose_cast_kernel<<<dim3(QKV_N / 32, HIDDEN / 32), 256, 0, stream>>>(w_qkv, wqT, HIDDEN, QKV_N);
  transpose_cast_kernel<<<dim3(HIDDEN / 32, QSZ / 32), 256, 0, stream>>>(w_o, woT, QSZ, HIDDEN);
  gemm_pipe_kernel<<<dim3((T_TOTAL / 128) * (QKV_N / 256)), 512, 0, stream>>>(
      hb, wqT, b_qkv, qkv, T_TOTAL, QKV_N, HIDDEN, QKV_N / 256);
  qk_rope_cast_kernel<<<T_TOTAL * 2560 / 256, 256, 0, stream>>>(qkv, positions, Qb, Kb);
  v_transpose_cast_kernel<<<dim3(S_LEN / 32, HD / 32, 16), 256, 0, stream>>>(qkv, Vtb);
  flash_mfma_kernel<<<dim3(S_LEN / 128, NH, 2), 512, 0, stream>>>(Qb, Kb, Vtb, attnb);
  gemm_pipe_kernel<<<dim3((T_TOTAL / 128) * (HIDDEN / 256)), 512, 0, stream>>>(
      attnb, woT, b_o, out, T_TOTAL, HIDDEN, QSZ, HIDDEN / 256);
}

// Round 7
// 864.323 us; speedup vs baseline: 1.7784x; 1.0269x over previous
//
#include <hip/hip_runtime.h>
#include <cstdint>
#include <math.h>

#define T_TOTAL 4096
#define S_LEN   2048
#define NH      32
#define NKV     8
#define HD      128
#define HIDDEN  4096
#define QSZ     4096
#define KVSZ    1024
#define QKV_N   6144
#define SCALE_F 0.08838834764831843f   // 128^-0.5

typedef __bf16 bf16x8 __attribute__((ext_vector_type(8)));
typedef float  f32x4  __attribute__((ext_vector_type(4)));
typedef unsigned short u16;
typedef unsigned int   u32;
typedef u16 u16x8 __attribute__((ext_vector_type(8)));
typedef u16 u16x4 __attribute__((ext_vector_type(4)));

__device__ __forceinline__ u16 f2bf(float f) {
  u32 b = __float_as_uint(f);
  b += 0x7FFFu + ((b >> 16) & 1u);      // round-to-nearest-even
  return (u16)(b >> 16);
}

// async global->LDS, 16B per lane; LDS dst MUST be uniform base + lane*16
__device__ __forceinline__ void async_copy16(const u16* g, u16* l) {
  __builtin_amdgcn_global_load_lds(
      (const __attribute__((address_space(1))) void*)(g),
      (__attribute__((address_space(3))) void*)(l), 16, 0, 0);
}

// ---------------- fp32 -> bf16 cast (vectorized) ----------------
__global__ __launch_bounds__(256) void cast_bf16_kernel(const float4* __restrict__ in,
                                                        ushort4* __restrict__ out, int n4) {
  int i = blockIdx.x * 256 + threadIdx.x;
  if (i >= n4) return;
  float4 v = in[i];
  ushort4 o;
  o.x = f2bf(v.x); o.y = f2bf(v.y); o.z = f2bf(v.z); o.w = f2bf(v.w);
  out[i] = o;
}

// ---------------- fp32 [R][C] -> bf16 [C][R] transpose-cast ----------------
__global__ __launch_bounds__(256) void transpose_cast_kernel(const float* __restrict__ in,
                                                             u16* __restrict__ out, int R, int C) {
  __shared__ float tile[32][33];
  int bx = blockIdx.x * 32;
  int by = blockIdx.y * 32;
  int tx = threadIdx.x & 31, ty = threadIdx.x >> 5;
  for (int i = ty; i < 32; i += 8)
    tile[i][tx] = in[(size_t)(by + i) * C + bx + tx];
  __syncthreads();
  for (int i = ty; i < 32; i += 8)
    out[(size_t)(bx + i) * R + by + tx] = f2bf(tile[tx][i]);
}

// ---------------- fine-phase pipelined bf16 MFMA GEMM: C = A * Bt^T + bias ----------------
// BM=BN=256, BK=32, 512 thr (8 waves as 2Mx4N, each 128x64 out). Per phase:
// {vmcnt(4); s_barrier; stage tile t+2 (4 gload_lds); 12 ds_read_b128; lgkmcnt(0);
//  setprio(1); 32 MFMA; setprio(0)} — ONE barrier per phase, counted vmcnt (T3+T4).
// 3-slot ring, 96 KB -> 1 block/CU (m201 precedent: fine-phase schedules carry
// 1 blk/CU; round-3's failure was the 2-barrier drain, removed here).
// Round-6's BM=128 doubled L2-miss traffic (FETCH 352->710 MB) — 256^2 restores
// panel reuse while keeping round-6's schedule (which lifted MfmaUtil 33->38.6).
// XOR swizzle identical to the measured-0-conflict layout.
// Single-barrier safety: a wave stages into slot (t+2)%3 only after the iter-t
// barrier, which all waves reach only after lgkmcnt(0)-complete reads of slot t;
// slot (t+2)%3 held tile t-1, fully consumed before that barrier.
__global__ __launch_bounds__(512) void gemm_pipe_kernel(const u16* __restrict__ A,
                                                        const u16* __restrict__ Bt,
                                                        const float* __restrict__ bias,
                                                        float* __restrict__ C,
                                                        int M, int N, int K, int nbn) {
  __shared__ u16 lds[3][16384];   // slot: A[256x32] (8192 u16) | B[256x32] (8192 u16) = 32 KB
  const int tid  = threadIdx.x;
  const int lane = tid & 63, wave = tid >> 6;
  const int quad = lane >> 4, l16 = lane & 15;
  const int wm = (wave >> 2) * 128;   // wave M-offset (2 rows of waves)
  const int wn = (wave & 3) * 64;     // wave N-offset (4 cols of waves)

  // XCD-aware bijective swizzle (both call sites: gridDim.x % 8 == 0)
  const int cpx = gridDim.x >> 3;
  const int logical = (blockIdx.x & 7) * cpx + (blockIdx.x >> 3);
  const int bm = logical / nbn, bn = logical % nbn;

  // Staging: rows of 32 bf16 = 4 chunks of 16B. Thread t owns row t>>2, chunk t&3,
  // for both the low half (rows 0-127) and high half (rows 128-255) of A and B.
  // LDS dest linear (gload_lds requirement); XOR swizzle carried by global source:
  // g_chunk = (t&3) ^ ((row>>1)&3) = (t&3) ^ ((t>>3)&3).
  const int gch = ((tid & 3) ^ ((tid >> 3) & 3)) * 8;
  const u16* gA0 = A  + (size_t)(bm * 256 + (tid >> 2)) * K + gch;
  const u16* gA1 = gA0 + (size_t)128 * K;
  const u16* gB0 = Bt + (size_t)(bn * 256 + (tid >> 2)) * K + gch;
  const u16* gB1 = gB0 + (size_t)128 * K;

  const int NT = K >> 5;
  // prologue: stage tiles 0,1 into slots 0,1 (4 loads each, issue order = vmcnt order)
#pragma unroll
  for (int pt = 0; pt < 2; ++pt) {
    int kt = pt * 32;
    async_copy16(gA0 + kt, &lds[pt][tid * 8]);
    async_copy16(gA1 + kt, &lds[pt][4096 + tid * 8]);
    async_copy16(gB0 + kt, &lds[pt][8192 + tid * 8]);
    async_copy16(gB1 + kt, &lds[pt][12288 + tid * 8]);
  }

  // frag-read swizzled chunk: quad ^ ((row>>1)&3); row low bits come from l16.
  const int sw = (quad ^ ((l16 >> 1) & 3)) * 8;
  f32x4 acc[8][4] = {};
  int sl = 0;                     // slot of tile t
  for (int t = 0; t < NT; ++t) {
    if (t + 1 < NT) asm volatile("s_waitcnt vmcnt(4)" ::: "memory");  // tile t landed; t+1 in flight
    else            asm volatile("s_waitcnt vmcnt(0)" ::: "memory");
    __builtin_amdgcn_s_barrier();  // tile t visible; slot s2's old reads all done

    int s2 = (sl == 0) ? 2 : sl - 1;   // (sl+2)%3 — slot that held tile t-1
    if (t + 2 < NT) {                  // stage tile t+2; loads fly across phases
      int kt = (t + 2) * 32;
      async_copy16(gA0 + kt, &lds[s2][tid * 8]);
      async_copy16(gA1 + kt, &lds[s2][4096 + tid * 8]);
      async_copy16(gB0 + kt, &lds[s2][8192 + tid * 8]);
      async_copy16(gB1 + kt, &lds[s2][12288 + tid * 8]);
    }

    const u16* sAt = lds[sl];
    const u16* sBt = &lds[sl][8192];
    bf16x8 af[8], bfr[4];
#pragma unroll
    for (int i = 0; i < 8; ++i)
      af[i] = *(const bf16x8*)&sAt[(wm + i * 16 + l16) * 32 + sw];
#pragma unroll
    for (int j = 0; j < 4; ++j)
      bfr[j] = *(const bf16x8*)&sBt[(wn + j * 16 + l16) * 32 + sw];
    asm volatile("s_waitcnt lgkmcnt(0)" ::: "memory");

    __builtin_amdgcn_s_setprio(1);
#pragma unroll
    for (int i = 0; i < 8; ++i)
#pragma unroll
      for (int j = 0; j < 4; ++j)
        acc[i][j] = __builtin_amdgcn_mfma_f32_16x16x32_bf16(af[i], bfr[j], acc[i][j], 0, 0, 0);
    __builtin_amdgcn_s_setprio(0);

    sl = (sl == 2) ? 0 : sl + 1;
  }

  // epilogue: bias + fp32 store (row = bm*256+wm+i*16+quad*4+r, col = bn*256+wn+j*16+l16)
#pragma unroll
  for (int i = 0; i < 8; ++i) {
    int row0 = bm * 256 + wm + i * 16 + quad * 4;
#pragma unroll
    for (int j = 0; j < 4; ++j) {
      int col = bn * 256 + wn + j * 16 + l16;
      float bi = bias[col];
#pragma unroll
      for (int r = 0; r < 4; ++r)
        C[(size_t)(row0 + r) * N + col] = acc[i][j][r] + bi;
    }
  }
}

// ---------------- RoPE + cast + layout for Q,K (bf16), scale folded into Q ----------------
__global__ __launch_bounds__(256) void qk_rope_cast_kernel(const float* __restrict__ qkv,
                                                           const int* __restrict__ pos,
                                                           u16* __restrict__ Qb,
                                                           u16* __restrict__ Kb) {
  int idx = blockIdx.x * 256 + threadIdx.x;   // T * 40 heads * 64 pairs
  int t = idx / 2560;
  int rem = idx - t * 2560;
  int head = rem >> 6, i = rem & 63;
  int b = t >> 11, s = t & 2047;
  float p = (float)pos[t];
  float inv = exp2f(-(float)i * 0.25952563f);   // (1e5)^(-2i/128)
  float f = p * inv;
  float sn, cs;
  sincosf(f, &sn, &cs);
  if (head < NH) {
    const float* src = qkv + (size_t)t * QKV_N + head * HD;
    float x1 = src[i], x2 = src[i + 64];
    u16* dst = Qb + (((size_t)(b * NH + head)) * S_LEN + s) * HD;
    dst[i]      = f2bf((x1 * cs - x2 * sn) * SCALE_F);
    dst[i + 64] = f2bf((x2 * cs + x1 * sn) * SCALE_F);
  } else {
    int kh = head - NH;
    const float* src = qkv + (size_t)t * QKV_N + QSZ + kh * HD;
    float x1 = src[i], x2 = src[i + 64];
    u16* dst = Kb + (((size_t)(b * NKV + kh)) * S_LEN + s) * HD;
    dst[i]      = f2bf(x1 * cs - x2 * sn);
    dst[i + 64] = f2bf(x2 * cs + x1 * sn);
  }
}

// ---------------- V transpose-cast: fp32 qkv -> bf16 Vtb [b][kvh][d=128][s=2048] ----------------
__global__ __launch_bounds__(256) void v_transpose_cast_kernel(const float* __restrict__ qkv,
                                                               u16* __restrict__ Vtb) {
  __shared__ float tile[32][33];
  int st = blockIdx.x * 32;
  int dt = blockIdx.y * 32;
  int bk = blockIdx.z;                      // b*8 + kvh
  int b = bk >> 3, kvh = bk & 7;
  int tx = threadIdx.x & 31, ty = threadIdx.x >> 5;
  const float* src = qkv + (size_t)(b * S_LEN) * QKV_N + QSZ + KVSZ + kvh * HD;
  for (int i = ty; i < 32; i += 8)
    tile[i][tx] = src[(size_t)(st + i) * QKV_N + dt + tx];
  __syncthreads();
  u16* dst = Vtb + (size_t)bk * HD * S_LEN;
  for (int i = ty; i < 32; i += 8)
    dst[(size_t)(dt + i) * S_LEN + st + tx] = f2bf(tile[tx][i]);
}

// ---------------- MFMA flash attention (causal, GQA 4:1) ----------------
// 128 q-rows per block, 8 waves (512 thr). Swapped-operand: QK^T as mfma(K,Q) ->
// S^T (lane = q-row, in-lane softmax); PV as mfma(Vt,P) -> O^T (per-lane alpha).
// XOR-swizzled LDS. Defer-max (T13). Causal wave-uniform skip of masked tiles.
// Round-6 diagnosis: LDS-BW-bound (~34 b128 DS ops/wave-iter = ~3200cy LDS-unit
// time per block-iter; MfmaUtil 12%). Fix queued: 32x32 MFMA (2x FLOP per LDS
// byte). Untouched this round for clean GEMM attribution.
__global__ __launch_bounds__(512) void flash_mfma_kernel(const u16* __restrict__ Qb,
                                                         const u16* __restrict__ Kb,
                                                         const u16* __restrict__ Vtb,
                                                         u16* __restrict__ attn) {
  const int qti = gridDim.x - 1 - blockIdx.x;   // long blocks launch first
  const int h = blockIdx.y, b = blockIdx.z;
  const int kvh = h >> 2;
  const int tid = threadIdx.x;
  const int lane = tid & 63, wave = tid >> 6;
  const int quad = lane >> 4, l16 = lane & 15;

  // 48 KB: sK 64x128 (16K) | sVt 128x64 (16K) | sP 8 waves x 16x64 (16K)
  __shared__ u16 smem[24576];
  u16* sK  = smem;
  u16* sVt = smem + 8192;
  u16* sPw = smem + 16384 + wave * 1024;

  // Q fragment (B-operand): lane l16 = q-row, elems = d-chunk quad*8+j
  bf16x8 qf[4];
  {
    const u16* qrow = Qb + (((size_t)(b * NH + h)) * S_LEN + (size_t)qti * 128 + wave * 16 + l16) * HD;
#pragma unroll
    for (int kc = 0; kc < 4; ++kc)
      qf[kc] = *(const bf16x8*)(qrow + kc * 32 + quad * 8);
  }

  f32x4 acc[8] = {};       // O^T: col l16 = q, rows quad*4+r = d within db*16
  float m_r = -INFINITY;   // per-lane running max for row q = l16
  float l_r = 0.f;

  const u16* Kbase = Kb  + ((size_t)(b * NKV + kvh)) * S_LEN * HD;
  const u16* Vbase = Vtb + ((size_t)(b * NKV + kvh)) * HD * S_LEN;

  // register prefetch buffers for next K/V tile (512 threads: 2 chunks each)
  u16x8 kv[2], vv[2];
#pragma unroll
  for (int i = 0; i < 2; ++i) {
    int c = i * 512 + tid;
    kv[i] = *(const u16x8*)(Kbase + (size_t)(c >> 4) * HD + (c & 15) * 8);
    vv[i] = *(const u16x8*)(Vbase + (size_t)(c >> 3) * S_LEN + (c & 7) * 8);
  }

  const int nkt = 2 * qti + 2;                 // 64-wide k-tiles for this block
  const int lastkt = 2 * qti + (wave >> 2);    // last useful tile for this wave

  for (int kt = 0; kt < nkt; ++kt) {
    __syncthreads();   // previous compute done, LDS reusable
#pragma unroll
    for (int i = 0; i < 2; ++i) {
      int c = i * 512 + tid;
      int kr = c >> 4;
      *(u16x8*)&sK[(kr * 128 + (c & 15) * 8) ^ ((kr & 7) << 3)] = kv[i];
      int vr = c >> 3;
      *(u16x8*)&sVt[(vr * 64 + (c & 7) * 8) ^ ((vr & 7) << 3)] = vv[i];
    }
    __syncthreads();   // staging visible

    if (kt + 1 < nkt) {   // prefetch next tile; vmcnt wait lands at next iter's LDS write
#pragma unroll
      for (int i = 0; i < 2; ++i) {
        int c = i * 512 + tid;
        kv[i] = *(const u16x8*)(Kbase + (size_t)((kt + 1) * 64 + (c >> 4)) * HD + (c & 15) * 8);
        vv[i] = *(const u16x8*)(Vbase + (size_t)(c >> 3) * S_LEN + (kt + 1) * 64 + (c & 7) * 8);
      }
    }

    if (kt > lastkt) continue;   // fully-masked tile for this wave (wave-uniform)

    // QK^T swapped: S^T[k][q] — A = K-frag (m = k-row), B = Q-frag (n = q-row)
    f32x4 s[4] = {};
#pragma unroll
    for (int kc = 0; kc < 4; ++kc) {
#pragma unroll
      for (int nb = 0; nb < 4; ++nb) {
        bf16x8 kf = *(const bf16x8*)&sK[((nb * 16 + l16) * 128 + kc * 32 + quad * 8) ^ ((l16 & 7) << 3)];
        s[nb] = __builtin_amdgcn_mfma_f32_16x16x32_bf16(kf, qf[kc], s[nb], 0, 0, 0);
      }
    }

    if (kt == lastkt) {   // causal mask on this wave's diagonal tile
      int qg = qti * 128 + wave * 16 + l16;
      int k0 = kt * 64;
#pragma unroll
      for (int nb = 0; nb < 4; ++nb)
#pragma unroll
        for (int r = 0; r < 4; ++r)
          if (k0 + nb * 16 + quad * 4 + r > qg) s[nb][r] = -1e30f;
    }

    // online softmax with defer-max (T13, THR=8): lane owns row q = l16
    float mx = -1e30f;
#pragma unroll
    for (int nb = 0; nb < 4; ++nb)
#pragma unroll
      for (int r = 0; r < 4; ++r)
        mx = fmaxf(mx, s[nb][r]);
    float alpha = 1.f;
    if (!__all(mx - m_r <= 8.f)) {
      mx = fmaxf(mx, __shfl_xor(mx, 16));
      mx = fmaxf(mx, __shfl_xor(mx, 32));
      float mnew = fmaxf(m_r, mx);
      alpha = __expf(m_r - mnew);
      m_r = mnew;
#pragma unroll
      for (int db = 0; db < 8; ++db)
#pragma unroll
        for (int r = 0; r < 4; ++r)
          acc[db][r] *= alpha;
    }
    float rs = 0.f;
#pragma unroll
    for (int nb = 0; nb < 4; ++nb)
#pragma unroll
      for (int r = 0; r < 4; ++r) {
        float p = __expf(s[nb][r] - m_r);
        s[nb][r] = p;
        rs += p;
      }
    rs += __shfl_xor(rs, 16);
    rs += __shfl_xor(rs, 32);
    l_r = l_r * alpha + rs;

    // P -> LDS: per lane 4x ds_write_b64, wave-private, swizzled
#pragma unroll
    for (int nb = 0; nb < 4; ++nb) {
      u16x4 pk;
#pragma unroll
      for (int r = 0; r < 4; ++r) pk[r] = f2bf(s[nb][r]);
      *(u16x4*)&sPw[(l16 * 64 + nb * 16 + quad * 4) ^ ((l16 & 7) << 3)] = pk;
    }

    // PV swapped: O^T += V^T * P^T — A = Vt-frag (m = d), B = P-frag (n = q)
#pragma unroll
    for (int ch = 0; ch < 2; ++ch) {
      bf16x8 pf = *(const bf16x8*)&sPw[(l16 * 64 + ch * 32 + quad * 8) ^ ((l16 & 7) << 3)];
#pragma unroll
      for (int db = 0; db < 8; ++db) {
        bf16x8 vf = *(const bf16x8*)&sVt[((db * 16 + l16) * 64 + ch * 32 + quad * 8) ^ ((l16 & 7) << 3)];
        acc[db] = __builtin_amdgcn_mfma_f32_16x16x32_bf16(vf, pf, acc[db], 0, 0, 0);
      }
    }
  }

  // epilogue: normalize (per-lane), transpose via LDS (reuse smem), coalesced store
  float invl = 1.0f / l_r;
  __syncthreads();   // all waves done with sK/sVt reads
  u16* sOw = &smem[wave * 2048];   // per-wave [16 q][128 d] bf16, swizzled
#pragma unroll
  for (int db = 0; db < 8; ++db) {
    u16x4 pk;
#pragma unroll
    for (int r = 0; r < 4; ++r) pk[r] = f2bf(acc[db][r] * invl);
    *(u16x4*)&sOw[(l16 * 128 + db * 16 + quad * 4) ^ ((l16 & 7) << 3)] = pk;
  }
  // wave-private region: no barrier needed between write and read
#pragma unroll
  for (int p = 0; p < 4; ++p) {
    int row = p * 4 + quad;
    u16x8 o = *(const u16x8*)&sOw[(row * 128 + l16 * 8) ^ ((row & 7) << 3)];
    int q = qti * 128 + wave * 16 + row;
    *(u16x8*)(attn + ((size_t)(b * S_LEN + q)) * QSZ + (size_t)h * HD + l16 * 8) = o;
  }
}

extern "C" void kernel_launch(void* const* d_in, const int* in_sizes, int n_in,
                              void* d_out, int out_size, void* d_ws, size_t ws_size,
                              hipStream_t stream) {
  const float* hidden    = (const float*)d_in[0];
  const int*   positions = (const int*)d_in[1];
  const float* w_qkv     = (const float*)d_in[2];
  const float* b_qkv     = (const float*)d_in[3];
  const float* w_o       = (const float*)d_in[4];
  const float* b_o       = (const float*)d_in[5];
  float* out = (float*)d_out;

  char* ws = (char*)d_ws;
  const size_t MB = 1024 * 1024;
  u16*   hb    = (u16*)ws;                       // 0..32 MB   (gemm1 A)
  u16*   wqT   = (u16*)(ws + 32  * MB);          // 32..80 MB  (gemm1 B)
  u16*   woT   = (u16*)(ws + 80  * MB);          // 80..112 MB (gemm2 B)
  float* qkv   = (float*)(ws + 112 * MB);        // 112..208 MB
  u16*   attnb = (u16*)(ws + 208 * MB);          // 208..240 MB
  // overlays — alive only after gemm1 has consumed hb/wqT:
  u16*   Qb    = (u16*)ws;                       // 0..32 MB
  u16*   Kb    = (u16*)(ws + 32 * MB);           // 32..40 MB
  u16*   Vtb   = (u16*)(ws + 40 * MB);           // 40..48 MB

  cast_bf16_kernel<<<T_TOTAL * HIDDEN / 4 / 256, 256, 0, stream>>>(
      (const float4*)hidden, (ushort4*)hb, T_TOTAL * HIDDEN / 4);
  transpose_cast_kernel<<<dim3(QKV_N / 32, HIDDEN / 32), 256, 0, stream>>>(w_qkv, wqT, HIDDEN, QKV_N);
  transpose_cast_kernel<<<dim3(HIDDEN / 32, QSZ / 32), 256, 0, stream>>>(w_o, woT, QSZ, HIDDEN);
  gemm_pipe_kernel<<<dim3((T_TOTAL / 256) * (QKV_N / 256)), 512, 0, stream>>>(
      hb, wqT, b_qkv, qkv, T_TOTAL, QKV_N, HIDDEN, QKV_N / 256);
  qk_rope_cast_kernel<<<T_TOTAL * 2560 / 256, 256, 0, stream>>>(qkv, positions, Qb, Kb);
  v_transpose_cast_kernel<<<dim3(S_LEN / 32, HD / 32, 16), 256, 0, stream>>>(qkv, Vtb);
  flash_mfma_kernel<<<dim3(S_LEN / 128, NH, 2), 512, 0, stream>>>(Qb, Kb, Vtb, attnb);
  gemm_pipe_kernel<<<dim3((T_TOTAL / 256) * (HIDDEN / 256)), 512, 0, stream>>>(
      attnb, woT, b_o, out, T_TOTAL, HIDDEN, QSZ, HIDDEN / 256);
}